// Round 5
// baseline (208.375 us; speedup 1.0000x reference)
//
#include <hip/hip_runtime.h>
#include <stdint.h>

// SplitAttention: x->(x_tok|x_pos); Q=x_pos@Wq K=x_pos@Wk V=x_tok@Wv;
// causal 16-head attention (d=64); out = attn @ Wo. All MFMA bf16.
//
// R11: attn moves 2 -> 4 q-groups per wave (wave owns 64 q-rows, block owns
// a 256-row q-tile, grid (64,8)): each K/V ds_read_b128 now feeds 72 MFMA
// per 16 reads (was 30/16) -- kernel was LDS-read-pipe bound ~4:1.
// __launch_bounds__(256,2) (NOT 4: R9/R10's (256,4) made the allocator
// squeeze 76->64 VGPR with ~10 spilled regs = +11MB scratch writes).
// Single barrier/iter K/V double-buffer kept from R10. GEMMs unchanged (R8).

typedef unsigned short u16;
typedef __bf16 bf16;
typedef bf16 bf16x8 __attribute__((ext_vector_type(8)));
typedef u16 u16x8 __attribute__((ext_vector_type(8)));
typedef u16 u16x4 __attribute__((ext_vector_type(4)));
typedef float f32x4 __attribute__((ext_vector_type(4)));
typedef uint32_t u32x4 __attribute__((ext_vector_type(4)));

__device__ __forceinline__ u16 cvt_bf16(float f) {
  uint32_t u = __builtin_bit_cast(uint32_t, f);
  u += 0x7FFFu + ((u >> 16) & 1u);   // RNE
  return (u16)(u >> 16);
}

// pack two f32 -> (bf16 lo | bf16 hi) with +0.5ulp rounding, one v_perm_b32
__device__ __forceinline__ uint32_t pack2_bf16(float lo, float hi) {
  uint32_t a = __builtin_bit_cast(uint32_t, lo) + 0x8000u;
  uint32_t b = __builtin_bit_cast(uint32_t, hi) + 0x8000u;
  return __builtin_amdgcn_perm(b, a, 0x07060302u);
}

__device__ __forceinline__ f32x4 mfma_bf(bf16x8 a, bf16x8 b, f32x4 c) {
  return __builtin_amdgcn_mfma_f32_16x16x32_bf16(a, b, c, 0, 0, 0);
}

typedef __attribute__((address_space(1))) const uint32_t g_u32;
typedef __attribute__((address_space(3))) uint32_t l_u32;
__device__ __forceinline__ void gload16(const u16* g, u16* l) {
  __builtin_amdgcn_global_load_lds((g_u32*)g, (l_u32*)l, 16, 0, 0);
}

// ---------------- x -> bf16 tok/pos split
__global__ __launch_bounds__(256) void prep_x(
    const float* __restrict__ x, u16* __restrict__ xtok,
    u16* __restrict__ xpos) {
  int idx = blockIdx.x * 256 + threadIdx.x;
  int row = idx >> 8;
  int c4 = (idx & 255) * 4;
  float4 v = *(const float4*)(x + (size_t)row * 1024 + c4);
  u16x4 b = {cvt_bf16(v.x), cvt_bf16(v.y), cvt_bf16(v.z), cvt_bf16(v.w)};
  u16* dst = (c4 < 512) ? (xtok + (size_t)row * 512 + c4)
                        : (xpos + (size_t)row * 512 + c4 - 512);
  *(u16x4*)dst = b;
}

// ---------------- W[k][n] f32 -> Wt[n][k] bf16 (z=0..2: 512x1024; z=3: Wo 1024x1024)
__global__ __launch_bounds__(256) void prep_w(
    const float* __restrict__ Wq, const float* __restrict__ Wk,
    const float* __restrict__ Wv, const float* __restrict__ Wo,
    u16* __restrict__ Wt, u16* __restrict__ WoT) {
  const int z = blockIdx.z;
  const float* src = (z == 0) ? Wq : (z == 1) ? Wk : (z == 2) ? Wv : Wo;
  const int K = (z == 3) ? 1024 : 512;
  u16* dst = (z == 3) ? WoT : (Wt + (size_t)z * 1024 * 512);
  const int k0 = blockIdx.y * 64, n0 = blockIdx.x * 64;
  if (k0 >= K) return;
  __shared__ u16 T[64][68];
  const int tid = threadIdx.x;
  const int r = tid >> 4, c = (tid & 15) * 4;
#pragma unroll
  for (int i = 0; i < 4; i++) {
    float4 v = *(const float4*)(src + (size_t)(k0 + r + i * 16) * 1024 + n0 + c);
    u16x4 b = {cvt_bf16(v.x), cvt_bf16(v.y), cvt_bf16(v.z), cvt_bf16(v.w)};
    *(u16x4*)&T[r + i * 16][c] = b;
  }
  __syncthreads();
#pragma unroll
  for (int i = 0; i < 4; i++) {
    int n = r + i * 16;
    u16x4 v;
#pragma unroll
    for (int j = 0; j < 4; j++) v[j] = T[c + j][n];
    *(u16x4*)(dst + (size_t)(n0 + n) * K + k0 + c) = v;
  }
}

// ================= 256x256 8-phase GEMM core =================
// 512 threads = 8 waves (2M x 4N), per-wave C = 128x64.
// LDS: A[2 dbuf][2 s-half][128][64] + B same = 128 KiB.
// 16B-slot XOR swizzle: slot ^= (row&7), applied on the global source
// (linear LDS dest) and on ds_read addrs. Counted vmcnt(6) at phases 4/8.

#define LDA(P, S) { const u16* bp_ = rA + (P)*16384 + (S)*8192;              \
  af[0][0] = *(const bf16x8*)(bp_ + 0*1024 + colx0);                         \
  af[0][1] = *(const bf16x8*)(bp_ + 0*1024 + colx1);                         \
  af[1][0] = *(const bf16x8*)(bp_ + 1*1024 + colx0);                         \
  af[1][1] = *(const bf16x8*)(bp_ + 1*1024 + colx1);                         \
  af[2][0] = *(const bf16x8*)(bp_ + 2*1024 + colx0);                         \
  af[2][1] = *(const bf16x8*)(bp_ + 2*1024 + colx1);                         \
  af[3][0] = *(const bf16x8*)(bp_ + 3*1024 + colx0);                         \
  af[3][1] = *(const bf16x8*)(bp_ + 3*1024 + colx1); }

#define LDB(P, S, NB) { const u16* bp_ = rB + (P)*16384 + (S)*8192;          \
  bf[(NB)+0][0] = *(const bf16x8*)(bp_ + 0*1024 + colx0);                    \
  bf[(NB)+0][1] = *(const bf16x8*)(bp_ + 0*1024 + colx1);                    \
  bf[(NB)+1][0] = *(const bf16x8*)(bp_ + 1*1024 + colx0);                    \
  bf[(NB)+1][1] = *(const bf16x8*)(bp_ + 1*1024 + colx1); }

#define MM1(M_, N_, J_) { f32x4 c_ = acc[M_][N_];                            \
  c_ = mfma_bf(af[J_][0], bf[N_][0], c_);                                    \
  c_ = mfma_bf(af[J_][1], bf[N_][1], c_);                                    \
  acc[M_][N_] = c_; }

#define MM(MB, NB) MM1((MB)+0,(NB)+0,0) MM1((MB)+0,(NB)+1,0)                 \
                   MM1((MB)+1,(NB)+0,1) MM1((MB)+1,(NB)+1,1)                 \
                   MM1((MB)+2,(NB)+0,2) MM1((MB)+2,(NB)+1,2)                 \
                   MM1((MB)+3,(NB)+0,3) MM1((MB)+3,(NB)+1,3)

#define STA(P, S, KT) { const u16* s_ = gA + (size_t)(S)*64*Kd + (KT)*64;    \
  u16* d_ = lA + (P)*16384 + (S)*8192;                                       \
  gload16(s_, d_); gload16(s_ + (size_t)128*Kd, d_ + 4096); }

#define STB(P, S, KT) { const u16* s_ = gB + (size_t)(S)*32*Kd + (KT)*64;    \
  u16* d_ = lB + (P)*16384 + (S)*8192;                                       \
  gload16(s_, d_); gload16(s_ + (size_t)128*Kd, d_ + 4096); }

#define PH_MID  asm volatile("" ::: "memory"); __builtin_amdgcn_s_barrier(); \
  asm volatile("s_waitcnt lgkmcnt(0)" ::: "memory");                         \
  __builtin_amdgcn_s_setprio(1);

#define PH_END  __builtin_amdgcn_s_setprio(0);                               \
  asm volatile("" ::: "memory"); __builtin_amdgcn_s_barrier();

#define PH_END_VM  __builtin_amdgcn_s_setprio(0);                            \
  asm volatile("s_waitcnt vmcnt(6)" ::: "memory");                           \
  asm volatile("" ::: "memory"); __builtin_amdgcn_s_barrier();

template <int Kd>
__device__ __forceinline__ void gemm256_core(
    const u16* __restrict__ Aptr, const u16* __restrict__ Bptr,
    int m0, int n0, u16* smem, f32x4 (&acc)[8][4]) {
  constexpr int NKT = Kd / 64;
  constexpr int NI = NKT / 2;
  const int tid = threadIdx.x;
  const int lane = tid & 63;
  const int mrow = lane & 15, quad = lane >> 4;
  const int w = tid >> 6, wm2 = w >> 2, wn4 = w & 3;

  u16* As = smem;
  u16* Bs = smem + 32768;

  // staging: thread -> (row lr = tid>>3 (+64 rnd1), 16B slot sp = tid&7)
  const int lrs = tid >> 3, sp8 = tid & 7;
  const int slog = sp8 ^ (lrs & 7);          // pre-swizzled global slot
  const u16* gA = Aptr + (size_t)(m0 + (lrs & 63)) * Kd + slog * 8;
  const u16* gB =
      Bptr + (size_t)(n0 + ((lrs >> 5) << 6) + (lrs & 31)) * Kd + slog * 8;
  u16* lA = As + tid * 8;
  u16* lB = Bs + tid * 8;

  // reads: swizzled column offsets (u16 units), key = (mrow&7)*8
  const int colx0 = (quad * 8) ^ ((mrow & 7) * 8);
  const int colx1 = (32 + quad * 8) ^ ((mrow & 7) * 8);
  const u16* rA = As + (wm2 * 64 + mrow) * 64;
  const u16* rB = Bs + (wn4 * 32 + mrow) * 64;

  bf16x8 af[4][2], bf[4][2];

  // prologue: buf0 all 4 halves (kt=0), buf1 minus A_M1 (kt=1)
  STA(0, 0, 0) STB(0, 0, 0) STB(0, 1, 0) STA(0, 1, 0)
  STA(1, 0, 1) STB(1, 0, 1) STB(1, 1, 1)
  asm volatile("s_waitcnt vmcnt(6)" ::: "memory");
  asm volatile("" ::: "memory");
  __builtin_amdgcn_s_barrier();

  for (int i = 0; i < NI; ++i) {
    const int kt1 = 2 * i + 1;
    const int kt2 = (2 * i + 2 < NKT) ? 2 * i + 2 : NKT - 1;  // clamp keeps
    const int kt3 = (2 * i + 3 < NKT) ? 2 * i + 3 : NKT - 1;  // vmcnt math uniform
    // ph1: read A(M0),B(N0) of buf0; stage buf1.A_M1 (kt1)
    LDA(0, 0) LDB(0, 0, 0) STA(1, 1, kt1)
    PH_MID MM(0, 0) PH_END
    // ph2: read B(N1); stage buf0.A_M0 (kt2)
    LDB(0, 1, 2) STA(0, 0, kt2)
    PH_MID MM(0, 2) PH_END
    // ph3: read A(M1); stage buf0.B_N0
    LDA(0, 1) STB(0, 0, kt2)
    PH_MID MM(4, 2) PH_END
    // ph4: stage buf0.B_N1; vmcnt(6) gates buf1
    STB(0, 1, kt2)
    PH_MID MM(4, 0) PH_END_VM
    // ph5: buf1 K-tile; stage buf0.A_M1
    LDA(1, 0) LDB(1, 0, 0) STA(0, 1, kt2)
    PH_MID MM(0, 0) PH_END
    // ph6: stage buf1.A_M0 (kt3)
    LDB(1, 1, 2) STA(1, 0, kt3)
    PH_MID MM(0, 2) PH_END
    // ph7: stage buf1.B_N0
    LDA(1, 1) STB(1, 0, kt3)
    PH_MID MM(4, 2) PH_END
    // ph8: stage buf1.B_N1; vmcnt(6) gates buf0
    STB(1, 1, kt3)
    PH_MID MM(4, 0) PH_END_VM
  }
  asm volatile("s_waitcnt vmcnt(0)" ::: "memory");  // drain clamped tail stages
  __builtin_amdgcn_s_barrier();
}

// ---------------- QKV projection, 256x256 8-phase
__global__ __launch_bounds__(512, 2) void gemm_qkv256(
    const u16* __restrict__ xtok, const u16* __restrict__ xpos,
    const u16* __restrict__ Wt, u16* __restrict__ qkv,
    u16* __restrict__ vperm) {
  const int z = blockIdx.z;
  const u16* A = (z == 2) ? xtok : xpos;
  const u16* Bt = Wt + (size_t)z * 1024 * 512;
  u16* outp = qkv + (size_t)z * (64u * 2048u * 64u);
  const float osc = (z == 0) ? 0.18033688011112042f : 1.0f;  // 0.125*log2e
  const int m0 = blockIdx.y * 256, n0 = blockIdx.x * 256;

  __shared__ __align__(16) u16 smem[65536];
  f32x4 acc[8][4];
#pragma unroll
  for (int i = 0; i < 8; i++)
#pragma unroll
    for (int j = 0; j < 4; j++) acc[i][j] = (f32x4){0.f, 0.f, 0.f, 0.f};

  gemm256_core<512>(A, Bt, m0, n0, smem, acc);

  const int tid = threadIdx.x;
  const int lane = tid & 63;
  const int mrow = lane & 15, quad = lane >> 4;
  const int w = tid >> 6, wm2 = w >> 2, wn4 = w & 3;

  if (z != 2) {
#pragma unroll
    for (int mi = 0; mi < 8; mi++)
#pragma unroll
      for (int ni = 0; ni < 4; ni++)
#pragma unroll
        for (int r = 0; r < 4; r++) {
          int m = m0 + wm2 * 128 + mi * 16 + quad * 4 + r;
          int n = n0 + wn4 * 64 + ni * 16 + mrow;
          int bb = m >> 11, t = m & 2047;
          int h = n >> 6, d = n & 63;
          outp[(((size_t)(bb * 16 + h)) * 2048 + t) * 64 + d] =
              cvt_bf16(acc[mi][ni][r] * osc);
        }
  } else {
#pragma unroll
    for (int mi = 0; mi < 8; mi++)
#pragma unroll
      for (int ni = 0; ni < 4; ni++)
#pragma unroll
        for (int r = 0; r < 4; r++) {
          int m = m0 + wm2 * 128 + mi * 16 + quad * 4 + r;
          int n = n0 + wn4 * 64 + ni * 16 + mrow;
          int bb = m >> 11, t = m & 2047;
          int h = n >> 6, d = n & 63;
          int k6 = t & 63;
          int pos = (k6 & 32) + ((k6 >> 4) & 1) * 4 + ((k6 >> 2) & 3) * 8 +
                    (k6 & 3);
          vperm[(((size_t)(bb * 16 + h)) * 64 + d) * 2048 + (t & ~63) + pos] =
              cvt_bf16(acc[mi][ni][r]);
        }
  }
}

// ---------------- Output projection, 256x256 8-phase: aout @ WoT -> f32
__global__ __launch_bounds__(512, 2) void gemm_out256(
    const u16* __restrict__ Am, const u16* __restrict__ WoT,
    float* __restrict__ out) {
  const int m0 = blockIdx.y * 256, n0 = blockIdx.x * 256;

  __shared__ __align__(16) u16 smem[65536];
  f32x4 acc[8][4];
#pragma unroll
  for (int i = 0; i < 8; i++)
#pragma unroll
    for (int j = 0; j < 4; j++) acc[i][j] = (f32x4){0.f, 0.f, 0.f, 0.f};

  gemm256_core<1024>(Am, WoT, m0, n0, smem, acc);

  const int tid = threadIdx.x;
  const int lane = tid & 63;
  const int mrow = lane & 15, quad = lane >> 4;
  const int w = tid >> 6, wm2 = w >> 2, wn4 = w & 3;

#pragma unroll
  for (int mi = 0; mi < 8; mi++)
#pragma unroll
    for (int ni = 0; ni < 4; ni++)
#pragma unroll
      for (int r = 0; r < 4; r++) {
        int m = m0 + wm2 * 128 + mi * 16 + quad * 4 + r;
        int n = n0 + wn4 * 64 + ni * 16 + mrow;
        out[(size_t)m * 1024 + n] = acc[mi][ni][r];
      }
}

// ---------------- Flash attention (S^T / O^T, no max, 256-row q-tiles)
// 4 q-groups of 16 rows per wave (wave owns 64 q-rows): every K/V LDS
// fragment read feeds 72 MFMA per 16 reads. Grid (64,8), longest-first
// (qt = 7-by); blocks of one head land on one XCD (gid = bh + 64y) so K/V
// stays L2-local. K/V LDS double-buffered, ONE __syncthreads per k-iter;
// register prefetch issued before the barrier. Epilogue: two 32-row passes
// per wave through per-wave LDS (overlaid on K/V bufs after final barrier).
__global__ __launch_bounds__(256, 2) void attn(
    const u16* __restrict__ qkv, const u16* __restrict__ vperm,
    u16* __restrict__ aout) {
  const int bh = blockIdx.x;
  const int qt = 7 - blockIdx.y;   // 256-row q-tile, longest first
  const int bb = bh >> 4, h = bh & 15;
  const u16* Qp = qkv + (size_t)bh * (2048 * 64);
  const u16* Kp = qkv + (size_t)(64 + bh) * (2048 * 64);
  const u16* Vp = vperm + (size_t)bh * (64 * 2048);

  // [buf][section: K0,K1,V0,V1][64*32]
  __shared__ __align__(16) u16 smem[2][4][64 * 32];

  const int tid = threadIdx.x;
  const int lane = tid & 63;
  const int w = tid >> 6;
  const int mrow = lane & 15;
  const int quad = lane >> 4;
  const int srow = w * 16 + (lane >> 2);
  const int sc = (lane & 3) * 8;
  const int soff = srow * 32 + sc;

  const u16x8 onesu = {0x3F80, 0x3F80, 0x3F80, 0x3F80,
                       0x3F80, 0x3F80, 0x3F80, 0x3F80};
  const bf16x8 ones = __builtin_bit_cast(bf16x8, onesu);

  const u16* kgb = Kp + (size_t)srow * 64 + sc;   // + k0*64 per tile
  const u16* vgb = Vp + (size_t)srow * 2048 + sc; // + k0 per tile

  const int q0 = qt * 256;
  const int nk = 4 * qt + 4;
  const int qw = q0 + w * 64;                  // wave's first q row

  const u16* qbase = Qp + (size_t)(qw + mrow) * 64 + quad * 8;
  bf16x8 qf[4][2];
#pragma unroll
  for (int g = 0; g < 4; ++g) {
    qf[g][0] = *(const bf16x8*)(qbase + g * 16 * 64);
    qf[g][1] = *(const bf16x8*)(qbase + g * 16 * 64 + 32);
  }

  f32x4 o[4][4], ol[4];
#pragma unroll
  for (int g = 0; g < 4; ++g) {
#pragma unroll
    for (int dt = 0; dt < 4; ++dt) o[g][dt] = (f32x4){0.f, 0.f, 0.f, 0.f};
    ol[g] = (f32x4){0.f, 0.f, 0.f, 0.f};
  }

  // prefetch tile 0
  u16x8 ka0 = *(const u16x8*)kgb;
  u16x8 ka1 = *(const u16x8*)(kgb + 32);
  u16x8 va0 = *(const u16x8*)vgb;
  u16x8 va1 = *(const u16x8*)(vgb + 32);

  for (int it = 0; it < nk; ++it) {
    u16* buf = &smem[it & 1][0][0];
    *(u16x8*)(buf + 0 * 2048 + soff) = ka0;
    *(u16x8*)(buf + 1 * 2048 + soff) = ka1;
    *(u16x8*)(buf + 2 * 2048 + soff) = va0;
    *(u16x8*)(buf + 3 * 2048 + soff) = va1;

    if (it + 1 < nk) {   // issue next tile's loads; land during compute
      const int kn = (it + 1) * 64;
      ka0 = *(const u16x8*)(kgb + (size_t)kn * 64);
      ka1 = *(const u16x8*)(kgb + (size_t)kn * 64 + 32);
      va0 = *(const u16x8*)(vgb + kn);
      va1 = *(const u16x8*)(vgb + kn + 32);
    }

    __syncthreads();   // buf[it&1] visible; prior readers done at barrier it-1

    const int k0 = it * 64;
    if (k0 > qw + 63) continue;   // tile entirely above this wave's diagonal

    // S^T = K · Q^T  (C: row = key-in-tile = quad*4+r, col = q = mrow)
    f32x4 s[4][4];
#pragma unroll
    for (int nt = 0; nt < 4; ++nt) {
      bf16x8 kf0 = *(const bf16x8*)(buf + 0 * 2048 + (nt * 16 + mrow) * 32 + quad * 8);
      bf16x8 kf1 = *(const bf16x8*)(buf + 1 * 2048 + (nt * 16 + mrow) * 32 + quad * 8);
#pragma unroll
      for (int g = 0; g < 4; ++g) {
        f32x4 z = (f32x4){0.f, 0.f, 0.f, 0.f};
        z = mfma_bf(kf0, qf[g][0], z);
        s[g][nt] = mfma_bf(kf1, qf[g][1], z);
      }
    }

    if (k0 + 63 > qw) {   // diagonal region for this wave: causal mask
#pragma unroll
      for (int g = 0; g < 4; ++g)
#pragma unroll
        for (int nt = 0; nt < 4; ++nt)
#pragma unroll
          for (int r = 0; r < 4; ++r)
            if (k0 + nt * 16 + quad * 4 + r > qw + g * 16 + mrow)
              s[g][nt][r] = -1e30f;
    }
    // p = exp2(s), no max subtraction (|s| bounded << 127)
#pragma unroll
    for (int g = 0; g < 4; ++g)
#pragma unroll
      for (int nt = 0; nt < 4; ++nt)
#pragma unroll
        for (int r = 0; r < 4; ++r)
          s[g][nt][r] = __builtin_amdgcn_exp2f(s[g][nt][r]);

    // P^T B-frags packed from s[] via v_perm; l row-sum via ones A-frag
    bf16x8 pf[4][2];
#pragma unroll
    for (int g = 0; g < 4; ++g) {
      u32x4 pw0 = {pack2_bf16(s[g][0][0], s[g][0][1]),
                   pack2_bf16(s[g][0][2], s[g][0][3]),
                   pack2_bf16(s[g][1][0], s[g][1][1]),
                   pack2_bf16(s[g][1][2], s[g][1][3])};
      u32x4 pw1 = {pack2_bf16(s[g][2][0], s[g][2][1]),
                   pack2_bf16(s[g][2][2], s[g][2][3]),
                   pack2_bf16(s[g][3][0], s[g][3][1]),
                   pack2_bf16(s[g][3][2], s[g][3][3])};
      pf[g][0] = __builtin_bit_cast(bf16x8, pw0);
      pf[g][1] = __builtin_bit_cast(bf16x8, pw1);
      ol[g] = mfma_bf(ones, pf[g][0], ol[g]);
      ol[g] = mfma_bf(ones, pf[g][1], ol[g]);
    }

    // O^T += V^T · P^T  (each vf read feeds all 4 q-groups)
#pragma unroll
    for (int dt = 0; dt < 4; ++dt) {
      bf16x8 vf0 = *(const bf16x8*)(buf + 2 * 2048 + (dt * 16 + mrow) * 32 + quad * 8);
      bf16x8 vf1 = *(const bf16x8*)(buf + 3 * 2048 + (dt * 16 + mrow) * 32 + quad * 8);
#pragma unroll
      for (int g = 0; g < 4; ++g) {
        o[g][dt] = mfma_bf(vf0, pf[g][0], o[g][dt]);
        o[g][dt] = mfma_bf(vf1, pf[g][1], o[g][dt]);
      }
    }
  }

  __syncthreads();   // all K/V readers done; overlay per-wave Osh on smem
  u16* Osh = &smem[0][0][0] + w * 4096;   // per-wave region, 32 rows x 72

  // epilogue: normalize, transpose O^T -> O, store; two 32-row passes
#pragma unroll
  for (int pass = 0; pass < 2; ++pass) {
#pragma unroll
    for (int gl = 0; gl < 2; ++gl) {
      const int g = pass * 2 + gl;
      const float inv = 1.f / ol[g][0];
#pragma unroll
      for (int dt = 0; dt < 4; ++dt) {
        u16x4 b = {cvt_bf16(o[g][dt][0] * inv), cvt_bf16(o[g][dt][1] * inv),
                   cvt_bf16(o[g][dt][2] * inv), cvt_bf16(o[g][dt][3] * inv)};
        *(u16x4*)&Osh[(gl * 16 + mrow) * 72 + dt * 16 + quad * 4] = b;
      }
    }
#pragma unroll
    for (int p = 0; p < 4; ++p) {
      int ql = (lane >> 3) + 8 * p;
      int ch = lane & 7;
      u16x8 v = *(const u16x8*)&Osh[ql * 72 + ch * 8];
      int t = q0 + w * 64 + pass * 32 + ql;
      *(u16x8*)(aout + ((size_t)(bb * 2048 + t)) * 1024 + h * 64 + ch * 8) = v;
    }
  }
}

extern "C" void kernel_launch(void* const* d_in, const int* in_sizes, int n_in,
                              void* d_out, int out_size, void* d_ws, size_t ws_size,
                              hipStream_t stream) {
  const float* x  = (const float*)d_in[0];
  const float* Wq = (const float*)d_in[1];
  const float* Wk = (const float*)d_in[2];
  const float* Wv = (const float*)d_in[3];
  const float* Wo = (const float*)d_in[4];

  u16* qkv   = (u16*)d_ws;
  u16* vperm = qkv + (size_t)3 * 64 * 2048 * 64;
  u16* aout  = vperm + (size_t)64 * 64 * 2048;
  u16* xtok  = aout + (size_t)8192 * 1024;
  u16* xpos  = xtok + (size_t)8192 * 512;
  u16* Wt    = xpos + (size_t)8192 * 512;
  u16* WoT   = Wt + (size_t)3 * 1024 * 512;
  float* out = (float*)d_out;

  prep_x<<<dim3(8192), dim3(256), 0, stream>>>(x, xtok, xpos);
  prep_w<<<dim3(16, 16, 4), dim3(256), 0, stream>>>(Wq, Wk, Wv, Wo, Wt, WoT);
  gemm_qkv256<<<dim3(4, 32, 3), dim3(512), 0, stream>>>(xtok, xpos, Wt, qkv, vperm);
  attn<<<dim3(64, 8), dim3(256), 0, stream>>>(qkv, vperm, aout);
  gemm_out256<<<dim3(4, 32), dim3(512), 0, stream>>>(aout, WoT, out);
}

// Round 6
// 193.274 us; speedup vs baseline: 1.0781x; 1.0781x over previous
//
#include <hip/hip_runtime.h>
#include <stdint.h>

// SplitAttention: x->(x_tok|x_pos); Q=x_pos@Wq K=x_pos@Wk V=x_tok@Wv;
// causal 16-head attention (d=64); out = attn @ Wo. All MFMA bf16.
//
// R12: GEMMs retiled 256x256 -> 128x256 (gemm_out was 128 blocks = half
// machine idle; qkv was 384 = ragged 1.5 rounds). New 4-phase/K-tile-pair
// core, 3 stage-halves {A,B0,B1}/K-tile, counted vmcnt(2)/vmcnt(4), XCD
// swizzle (bijective, nwg=256). attn reverted to R10 structure (best
// measured, 52us) at launch_bounds(256,3): floor 3 waves/EU avoids the
// (256,4) allocator squeeze (76->64 VGPR, ~10 spills, +11MB scratch).

typedef unsigned short u16;
typedef __bf16 bf16;
typedef bf16 bf16x8 __attribute__((ext_vector_type(8)));
typedef u16 u16x8 __attribute__((ext_vector_type(8)));
typedef u16 u16x4 __attribute__((ext_vector_type(4)));
typedef float f32x4 __attribute__((ext_vector_type(4)));
typedef uint32_t u32x4 __attribute__((ext_vector_type(4)));

__device__ __forceinline__ u16 cvt_bf16(float f) {
  uint32_t u = __builtin_bit_cast(uint32_t, f);
  u += 0x7FFFu + ((u >> 16) & 1u);   // RNE
  return (u16)(u >> 16);
}

// pack two f32 -> (bf16 lo | bf16 hi) with +0.5ulp rounding, one v_perm_b32
__device__ __forceinline__ uint32_t pack2_bf16(float lo, float hi) {
  uint32_t a = __builtin_bit_cast(uint32_t, lo) + 0x8000u;
  uint32_t b = __builtin_bit_cast(uint32_t, hi) + 0x8000u;
  return __builtin_amdgcn_perm(b, a, 0x07060302u);
}

__device__ __forceinline__ f32x4 mfma_bf(bf16x8 a, bf16x8 b, f32x4 c) {
  return __builtin_amdgcn_mfma_f32_16x16x32_bf16(a, b, c, 0, 0, 0);
}

typedef __attribute__((address_space(1))) const uint32_t g_u32;
typedef __attribute__((address_space(3))) uint32_t l_u32;
__device__ __forceinline__ void gload16(const u16* g, u16* l) {
  __builtin_amdgcn_global_load_lds((g_u32*)g, (l_u32*)l, 16, 0, 0);
}

// ---------------- x -> bf16 tok/pos split
__global__ __launch_bounds__(256) void prep_x(
    const float* __restrict__ x, u16* __restrict__ xtok,
    u16* __restrict__ xpos) {
  int idx = blockIdx.x * 256 + threadIdx.x;
  int row = idx >> 8;
  int c4 = (idx & 255) * 4;
  float4 v = *(const float4*)(x + (size_t)row * 1024 + c4);
  u16x4 b = {cvt_bf16(v.x), cvt_bf16(v.y), cvt_bf16(v.z), cvt_bf16(v.w)};
  u16* dst = (c4 < 512) ? (xtok + (size_t)row * 512 + c4)
                        : (xpos + (size_t)row * 512 + c4 - 512);
  *(u16x4*)dst = b;
}

// ---------------- W[k][n] f32 -> Wt[n][k] bf16 (z=0..2: 512x1024; z=3: Wo 1024x1024)
__global__ __launch_bounds__(256) void prep_w(
    const float* __restrict__ Wq, const float* __restrict__ Wk,
    const float* __restrict__ Wv, const float* __restrict__ Wo,
    u16* __restrict__ Wt, u16* __restrict__ WoT) {
  const int z = blockIdx.z;
  const float* src = (z == 0) ? Wq : (z == 1) ? Wk : (z == 2) ? Wv : Wo;
  const int K = (z == 3) ? 1024 : 512;
  u16* dst = (z == 3) ? WoT : (Wt + (size_t)z * 1024 * 512);
  const int k0 = blockIdx.y * 64, n0 = blockIdx.x * 64;
  if (k0 >= K) return;
  __shared__ u16 T[64][68];
  const int tid = threadIdx.x;
  const int r = tid >> 4, c = (tid & 15) * 4;
#pragma unroll
  for (int i = 0; i < 4; i++) {
    float4 v = *(const float4*)(src + (size_t)(k0 + r + i * 16) * 1024 + n0 + c);
    u16x4 b = {cvt_bf16(v.x), cvt_bf16(v.y), cvt_bf16(v.z), cvt_bf16(v.w)};
    *(u16x4*)&T[r + i * 16][c] = b;
  }
  __syncthreads();
#pragma unroll
  for (int i = 0; i < 4; i++) {
    int n = r + i * 16;
    u16x4 v;
#pragma unroll
    for (int j = 0; j < 4; j++) v[j] = T[c + j][n];
    *(u16x4*)(dst + (size_t)(n0 + n) * K + k0 + c) = v;
  }
}

// ================= 128x256 4-phase GEMM core =================
// 512 threads = 8 waves (2M x 4N), per-wave C = 64x64, acc[4][4].
// LDS 96KB: A[2 buf][128][64] (32KB) + B[2 buf][2 half][128][64] (64KB).
// 3 stage-halves per K-tile: {A (2 loads), B_N0 (2), B_N1 (2)}.
// 16B-slot XOR swizzle slot^=(row&7): pre-swizzled global source (linear
// LDS dest) + swizzled ds_read col offsets.
// Phase pair per K-tile; 4 phases per iter (2 K-tiles). Stage schedule
// (queue audit): ph1 stages buf1.B1(kt1); ph2 stages buf0.A(kt2), gate
// vmcnt(2) [queue: b1.A,b1.B0 (prev ph4, 4) + b1.B1 (ph1, 2) + b0.A (2);
// buf1 ready needs first 6 retired -> allow 2]; ph3 stages buf0.B0(kt2);
// ph4 stages buf0.B1(kt2)+buf1.A(kt3)+buf1.B0(kt3), gate vmcnt(4)
// [queue: b0.A,b0.B0,b0.B1 (6) + b1.A,b1.B0 (4); buf0 ready -> allow 4].
// Every half overwritten >=1 barrier after its last read (A read ph1 /
// staged ph2; B0 read ph1 / staged ph3; B1 read ph2 / staged ph4).

#define MM1(M_, N_, J_) { f32x4 c_ = acc[M_][N_];                            \
  c_ = mfma_bf(af[J_][0], bf[N_][0], c_);                                    \
  c_ = mfma_bf(af[J_][1], bf[N_][1], c_);                                    \
  acc[M_][N_] = c_; }

#define XMM(NB) MM1(0,(NB)+0,0) MM1(0,(NB)+1,0) MM1(1,(NB)+0,1)              \
                MM1(1,(NB)+1,1) MM1(2,(NB)+0,2) MM1(2,(NB)+1,2)              \
                MM1(3,(NB)+0,3) MM1(3,(NB)+1,3)

#define XLDA(P) { const u16* bp_ = rA + (P)*8192;                            \
  af[0][0] = *(const bf16x8*)(bp_ + 0*1024 + colx0);                         \
  af[0][1] = *(const bf16x8*)(bp_ + 0*1024 + colx1);                         \
  af[1][0] = *(const bf16x8*)(bp_ + 1*1024 + colx0);                         \
  af[1][1] = *(const bf16x8*)(bp_ + 1*1024 + colx1);                         \
  af[2][0] = *(const bf16x8*)(bp_ + 2*1024 + colx0);                         \
  af[2][1] = *(const bf16x8*)(bp_ + 2*1024 + colx1);                         \
  af[3][0] = *(const bf16x8*)(bp_ + 3*1024 + colx0);                         \
  af[3][1] = *(const bf16x8*)(bp_ + 3*1024 + colx1); }

#define XLDB(P, NB) { const u16* bp_ = rB + (P)*16384;                       \
  bf[(NB)+0][0] = *(const bf16x8*)(bp_ + ((NB)+0)*1024 + colx0);             \
  bf[(NB)+0][1] = *(const bf16x8*)(bp_ + ((NB)+0)*1024 + colx1);             \
  bf[(NB)+1][0] = *(const bf16x8*)(bp_ + ((NB)+1)*1024 + colx0);             \
  bf[(NB)+1][1] = *(const bf16x8*)(bp_ + ((NB)+1)*1024 + colx1); }

#define XSTA(P, KT) { const u16* s_ = gA + (KT)*64;                          \
  u16* d_ = lA + (P)*8192;                                                   \
  gload16(s_, d_); gload16(s_ + (size_t)64*Kd, d_ + 4096); }

#define XSTB0(P, KT) { const u16* s_ = gB + (KT)*64;                         \
  u16* d_ = lB + (P)*16384;                                                  \
  gload16(s_, d_); gload16(s_ + (size_t)64*Kd, d_ + 4096); }

#define XSTB1(P, KT) { const u16* s_ = gB + (size_t)128*Kd + (KT)*64;        \
  u16* d_ = lB + (P)*16384 + 8192;                                           \
  gload16(s_, d_); gload16(s_ + (size_t)64*Kd, d_ + 4096); }

#define PH_MID  asm volatile("" ::: "memory"); __builtin_amdgcn_s_barrier(); \
  asm volatile("s_waitcnt lgkmcnt(0)" ::: "memory");                         \
  __builtin_amdgcn_s_setprio(1);

#define PH_END  __builtin_amdgcn_s_setprio(0);                               \
  asm volatile("" ::: "memory"); __builtin_amdgcn_s_barrier();

#define PH_END_VM2  __builtin_amdgcn_s_setprio(0);                           \
  asm volatile("s_waitcnt vmcnt(2)" ::: "memory");                           \
  asm volatile("" ::: "memory"); __builtin_amdgcn_s_barrier();

#define PH_END_VM4  __builtin_amdgcn_s_setprio(0);                           \
  asm volatile("s_waitcnt vmcnt(4)" ::: "memory");                           \
  asm volatile("" ::: "memory"); __builtin_amdgcn_s_barrier();

template <int Kd>
__device__ __forceinline__ void gemm128_core(
    const u16* __restrict__ Aptr, const u16* __restrict__ Bptr,
    int m0, int n0, u16* smem, f32x4 (&acc)[4][4]) {
  constexpr int NKT = Kd / 64;
  constexpr int NI = NKT / 2;
  const int tid = threadIdx.x;
  const int lane = tid & 63;
  const int mrow = lane & 15, quad = lane >> 4;
  const int w = tid >> 6, wm2 = w >> 2, wn4 = w & 3;

  // staging: thread -> (row = tid>>3 (+64 second load), 16B slot = tid&7)
  const int lrs = tid >> 3, sp8 = tid & 7;
  const int slog = sp8 ^ (lrs & 7);          // pre-swizzled global slot
  const u16* gA = Aptr + (size_t)(m0 + lrs) * Kd + slog * 8;
  const u16* gB = Bptr + (size_t)(n0 + lrs) * Kd + slog * 8;
  u16* lA = smem + tid * 8;
  u16* lB = smem + 16384 + tid * 8;

  // reads: swizzled column offsets (u16 units), key = (mrow&7)*8
  const int colx0 = (quad * 8) ^ ((mrow & 7) * 8);
  const int colx1 = (32 + quad * 8) ^ ((mrow & 7) * 8);
  const u16* rA = smem + (wm2 * 64 + mrow) * 64;
  const u16* rB = smem + 16384 + (wn4 >> 1) * 8192 + ((wn4 & 1) * 64 + mrow) * 64;

  bf16x8 af[4][2], bf[4][2];

  // prologue: buf0 {A,B0,B1}(kt0), buf1 {A,B0}(kt1); gate buf0 -> vmcnt(4)
  XSTA(0, 0) XSTB0(0, 0) XSTB1(0, 0)
  XSTA(1, 1) XSTB0(1, 1)
  asm volatile("s_waitcnt vmcnt(4)" ::: "memory");
  asm volatile("" ::: "memory");
  __builtin_amdgcn_s_barrier();

  for (int i = 0; i < NI; ++i) {
    const int kt1 = 2 * i + 1;
    const int kt2 = (2 * i + 2 < NKT) ? 2 * i + 2 : NKT - 1;  // clamp keeps
    const int kt3 = (2 * i + 3 < NKT) ? 2 * i + 3 : NKT - 1;  // vmcnt uniform
    // ph1: read buf0 {A, B ni0-1}; stage buf1.B1(kt1)
    XLDA(0) XLDB(0, 0) XSTB1(1, kt1)
    PH_MID XMM(0) PH_END
    // ph2: read buf0 {B ni2-3}; stage buf0.A(kt2); gate buf1
    XLDB(0, 2) XSTA(0, kt2)
    PH_MID XMM(2) PH_END_VM2
    // ph3: read buf1 {A, B ni0-1}; stage buf0.B0(kt2)
    XLDA(1) XLDB(1, 0) XSTB0(0, kt2)
    PH_MID XMM(0) PH_END
    // ph4: read buf1 {B ni2-3}; stage buf0.B1(kt2) + buf1.{A,B0}(kt3); gate buf0
    XLDB(1, 2) XSTB1(0, kt2) XSTA(1, kt3) XSTB0(1, kt3)
    PH_MID XMM(2) PH_END_VM4
  }
  asm volatile("s_waitcnt vmcnt(0)" ::: "memory");  // drain clamped tail stages
  __builtin_amdgcn_s_barrier();
}

// XCD-aware remap (bijective, nwg = 4*64 = 256, 256%8 == 0): slots on one
// XCD get consecutive work-ids -> A-panel shared in-XCD, B L2-resident.
__device__ __forceinline__ void xcd_remap(int& bx, int& by) {
  int flat = blockIdx.x + 4 * blockIdx.y;
  int wg = (flat & 7) * 32 + (flat >> 3);
  bx = wg & 3;
  by = wg >> 2;
}

// ---------------- QKV projection, 128x256 4-phase
__global__ __launch_bounds__(512, 1) void gemm_qkv128(
    const u16* __restrict__ xtok, const u16* __restrict__ xpos,
    const u16* __restrict__ Wt, u16* __restrict__ qkv,
    u16* __restrict__ vperm) {
  const int z = blockIdx.z;
  const u16* A = (z == 2) ? xtok : xpos;
  const u16* Bt = Wt + (size_t)z * 1024 * 512;
  u16* outp = qkv + (size_t)z * (64u * 2048u * 64u);
  const float osc = (z == 0) ? 0.18033688011112042f : 1.0f;  // 0.125*log2e
  int bx, by;
  xcd_remap(bx, by);
  const int m0 = by * 128, n0 = bx * 256;

  __shared__ __align__(16) u16 smem[49152];
  f32x4 acc[4][4];
#pragma unroll
  for (int i = 0; i < 4; i++)
#pragma unroll
    for (int j = 0; j < 4; j++) acc[i][j] = (f32x4){0.f, 0.f, 0.f, 0.f};

  gemm128_core<512>(A, Bt, m0, n0, smem, acc);

  const int tid = threadIdx.x;
  const int lane = tid & 63;
  const int mrow = lane & 15, quad = lane >> 4;
  const int w = tid >> 6, wm2 = w >> 2, wn4 = w & 3;

  if (z != 2) {
#pragma unroll
    for (int mi = 0; mi < 4; mi++)
#pragma unroll
      for (int ni = 0; ni < 4; ni++)
#pragma unroll
        for (int r = 0; r < 4; r++) {
          int m = m0 + wm2 * 64 + mi * 16 + quad * 4 + r;
          int n = n0 + wn4 * 64 + ni * 16 + mrow;
          int bb = m >> 11, t = m & 2047;
          int h = n >> 6, d = n & 63;
          outp[(((size_t)(bb * 16 + h)) * 2048 + t) * 64 + d] =
              cvt_bf16(acc[mi][ni][r] * osc);
        }
  } else {
#pragma unroll
    for (int mi = 0; mi < 4; mi++)
#pragma unroll
      for (int ni = 0; ni < 4; ni++)
#pragma unroll
        for (int r = 0; r < 4; r++) {
          int m = m0 + wm2 * 64 + mi * 16 + quad * 4 + r;
          int n = n0 + wn4 * 64 + ni * 16 + mrow;
          int bb = m >> 11, t = m & 2047;
          int h = n >> 6, d = n & 63;
          int k6 = t & 63;
          int pos = (k6 & 32) + ((k6 >> 4) & 1) * 4 + ((k6 >> 2) & 3) * 8 +
                    (k6 & 3);
          vperm[(((size_t)(bb * 16 + h)) * 64 + d) * 2048 + (t & ~63) + pos] =
              cvt_bf16(acc[mi][ni][r]);
        }
  }
}

// ---------------- Output projection, 128x256 4-phase: aout @ WoT -> f32
__global__ __launch_bounds__(512, 1) void gemm_out128(
    const u16* __restrict__ Am, const u16* __restrict__ WoT,
    float* __restrict__ out) {
  int bx, by;
  xcd_remap(bx, by);
  const int m0 = by * 128, n0 = bx * 256;

  __shared__ __align__(16) u16 smem[49152];
  f32x4 acc[4][4];
#pragma unroll
  for (int i = 0; i < 4; i++)
#pragma unroll
    for (int j = 0; j < 4; j++) acc[i][j] = (f32x4){0.f, 0.f, 0.f, 0.f};

  gemm128_core<1024>(Am, WoT, m0, n0, smem, acc);

  const int tid = threadIdx.x;
  const int lane = tid & 63;
  const int mrow = lane & 15, quad = lane >> 4;
  const int w = tid >> 6, wm2 = w >> 2, wn4 = w & 3;

#pragma unroll
  for (int mi = 0; mi < 4; mi++)
#pragma unroll
    for (int ni = 0; ni < 4; ni++)
#pragma unroll
      for (int r = 0; r < 4; r++) {
        int m = m0 + wm2 * 64 + mi * 16 + quad * 4 + r;
        int n = n0 + wn4 * 64 + ni * 16 + mrow;
        out[(size_t)m * 1024 + n] = acc[mi][ni][r];
      }
}

// ---------------- Flash attention (S^T / O^T, no max, 128-row q-tiles)
// R10 structure (best measured): one 128-row q-tile per block, grid
// (64,16), longest-first (qt = 15-by). 2 q-groups of 16 rows per wave.
// K/V LDS double-buffered, ONE __syncthreads per k-iter; register
// prefetch issued before the barrier. launch_bounds(256,3): floor 3
// waves/EU, cap 170 VGPR -> natural ~76-90 VGPR, no spill, LDS lets
// ~5 blocks/CU reside. Epilogue Osh overlays K/V bufs after a barrier.
__global__ __launch_bounds__(256, 3) void attn(
    const u16* __restrict__ qkv, const u16* __restrict__ vperm,
    u16* __restrict__ aout) {
  const int bh = blockIdx.x;
  const int qt = 15 - blockIdx.y;   // 128-row q-tile, longest first
  const int bb = bh >> 4, h = bh & 15;
  const u16* Qp = qkv + (size_t)bh * (2048 * 64);
  const u16* Kp = qkv + (size_t)(64 + bh) * (2048 * 64);
  const u16* Vp = vperm + (size_t)bh * (64 * 2048);

  // [buf][section: K0,K1,V0,V1][64*32]
  __shared__ __align__(16) u16 smem[2][4][64 * 32];

  const int tid = threadIdx.x;
  const int lane = tid & 63;
  const int w = tid >> 6;
  const int mrow = lane & 15;
  const int quad = lane >> 4;
  const int srow = w * 16 + (lane >> 2);
  const int sc = (lane & 3) * 8;
  const int soff = srow * 32 + sc;

  const u16x8 onesu = {0x3F80, 0x3F80, 0x3F80, 0x3F80,
                       0x3F80, 0x3F80, 0x3F80, 0x3F80};
  const bf16x8 ones = __builtin_bit_cast(bf16x8, onesu);

  const u16* kgb = Kp + (size_t)srow * 64 + sc;   // + k0*64 per tile
  const u16* vgb = Vp + (size_t)srow * 2048 + sc; // + k0 per tile

  const int q0 = qt * 128;
  const int nk = 2 * qt + 2;
  const int qw = q0 + w * 32;                  // wave's first q row

  const u16* qbase = Qp + (size_t)(qw + mrow) * 64 + quad * 8;
  const bf16x8 qf00 = *(const bf16x8*)qbase;             // g=0, d 0..31
  const bf16x8 qf01 = *(const bf16x8*)(qbase + 32);      // g=0, d 32..63
  const bf16x8 qf10 = *(const bf16x8*)(qbase + 16 * 64);       // g=1
  const bf16x8 qf11 = *(const bf16x8*)(qbase + 16 * 64 + 32);  // g=1

  f32x4 o[2][4], ol[2];
#pragma unroll
  for (int g = 0; g < 2; ++g) {
#pragma unroll
    for (int dt = 0; dt < 4; ++dt) o[g][dt] = (f32x4){0.f, 0.f, 0.f, 0.f};
    ol[g] = (f32x4){0.f, 0.f, 0.f, 0.f};
  }

  // prefetch tile 0
  u16x8 ka0 = *(const u16x8*)kgb;
  u16x8 ka1 = *(const u16x8*)(kgb + 32);
  u16x8 va0 = *(const u16x8*)vgb;
  u16x8 va1 = *(const u16x8*)(vgb + 32);

  for (int it = 0; it < nk; ++it) {
    u16* buf = &smem[it & 1][0][0];
    *(u16x8*)(buf + 0 * 2048 + soff) = ka0;
    *(u16x8*)(buf + 1 * 2048 + soff) = ka1;
    *(u16x8*)(buf + 2 * 2048 + soff) = va0;
    *(u16x8*)(buf + 3 * 2048 + soff) = va1;

    if (it + 1 < nk) {   // issue next tile's loads; land during compute
      const int kn = (it + 1) * 64;
      ka0 = *(const u16x8*)(kgb + (size_t)kn * 64);
      ka1 = *(const u16x8*)(kgb + (size_t)kn * 64 + 32);
      va0 = *(const u16x8*)(vgb + kn);
      va1 = *(const u16x8*)(vgb + kn + 32);
    }

    __syncthreads();   // buf[it&1] visible; prior readers done at barrier it-1

    const int k0 = it * 64;
    if (k0 > qw + 31) continue;   // tile entirely above causal diagonal

    // S^T = K · Q^T  (C: row = key-in-tile = quad*4+r, col = q = mrow)
    f32x4 s[2][4];
#pragma unroll
    for (int nt = 0; nt < 4; ++nt) {
      bf16x8 kf0 = *(const bf16x8*)(buf + 0 * 2048 + (nt * 16 + mrow) * 32 + quad * 8);
      bf16x8 kf1 = *(const bf16x8*)(buf + 1 * 2048 + (nt * 16 + mrow) * 32 + quad * 8);
      f32x4 z0 = (f32x4){0.f, 0.f, 0.f, 0.f};
      z0 = mfma_bf(kf0, qf00, z0);
      s[0][nt] = mfma_bf(kf1, qf01, z0);
      f32x4 z1 = (f32x4){0.f, 0.f, 0.f, 0.f};
      z1 = mfma_bf(kf0, qf10, z1);
      s[1][nt] = mfma_bf(kf1, qf11, z1);
    }

    if (k0 + 63 > qw) {   // diagonal tile for this wave: causal mask
#pragma unroll
      for (int g = 0; g < 2; ++g)
#pragma unroll
        for (int nt = 0; nt < 4; ++nt)
#pragma unroll
          for (int r = 0; r < 4; ++r)
            if (k0 + nt * 16 + quad * 4 + r > qw + g * 16 + mrow)
              s[g][nt][r] = -1e30f;
    }
    // p = exp2(s), no max subtraction (|s| bounded << 127)
#pragma unroll
    for (int g = 0; g < 2; ++g)
#pragma unroll
      for (int nt = 0; nt < 4; ++nt)
#pragma unroll
        for (int r = 0; r < 4; ++r)
          s[g][nt][r] = __builtin_amdgcn_exp2f(s[g][nt][r]);

    // P^T B-frags packed from s[] via v_perm
    bf16x8 pf[2][2];
#pragma unroll
    for (int g = 0; g < 2; ++g) {
      u32x4 pw0 = {pack2_bf16(s[g][0][0], s[g][0][1]),
                   pack2_bf16(s[g][0][2], s[g][0][3]),
                   pack2_bf16(s[g][1][0], s[g][1][1]),
                   pack2_bf16(s[g][1][2], s[g][1][3])};
      u32x4 pw1 = {pack2_bf16(s[g][2][0], s[g][2][1]),
                   pack2_bf16(s[g][2][2], s[g][2][3]),
                   pack2_bf16(s[g][3][0], s[g][3][1]),
                   pack2_bf16(s[g][3][2], s[g][3][3])};
      pf[g][0] = __builtin_bit_cast(bf16x8, pw0);
      pf[g][1] = __builtin_bit_cast(bf16x8, pw1);
      // l row-sum via ones A-frag
      ol[g] = mfma_bf(ones, pf[g][0], ol[g]);
      ol[g] = mfma_bf(ones, pf[g][1], ol[g]);
    }

    // O^T += V^T · P^T  (each vf read feeds both q-groups)
#pragma unroll
    for (int dt = 0; dt < 4; ++dt) {
      bf16x8 vf0 = *(const bf16x8*)(buf + 2 * 2048 + (dt * 16 + mrow) * 32 + quad * 8);
      bf16x8 vf1 = *(const bf16x8*)(buf + 3 * 2048 + (dt * 16 + mrow) * 32 + quad * 8);
      o[0][dt] = mfma_bf(vf0, pf[0][0], o[0][dt]);
      o[0][dt] = mfma_bf(vf1, pf[0][1], o[0][dt]);
      o[1][dt] = mfma_bf(vf0, pf[1][0], o[1][dt]);
      o[1][dt] = mfma_bf(vf1, pf[1][1], o[1][dt]);
    }
  }

  __syncthreads();   // all K/V readers done; reuse smem as Osh[4][32][72]
  u16* Osh = &smem[0][0][0];

  // epilogue: normalize, transpose O^T -> O through per-wave LDS, store
#pragma unroll
  for (int g = 0; g < 2; ++g) {
    const float inv = 1.f / ol[g][0];
#pragma unroll
    for (int dt = 0; dt < 4; ++dt)
#pragma unroll
      for (int r = 0; r < 4; ++r)
        Osh[(w * 32 + g * 16 + mrow) * 72 + dt * 16 + quad * 4 + r] =
            cvt_bf16(o[g][dt][r] * inv);
  }
#pragma unroll
  for (int p = 0; p < 4; ++p) {
    int ql = (lane >> 3) + 8 * p;
    int ch = lane & 7;
    u16x8 v = *(const u16x8*)&Osh[(w * 32 + ql) * 72 + ch * 8];
    int t = q0 + w * 32 + ql;
    *(u16x8*)(aout + ((size_t)(bb * 2048 + t)) * 1024 + h * 64 + ch * 8) = v;
  }
}

extern "C" void kernel_launch(void* const* d_in, const int* in_sizes, int n_in,
                              void* d_out, int out_size, void* d_ws, size_t ws_size,
                              hipStream_t stream) {
  const float* x  = (const float*)d_in[0];
  const float* Wq = (const float*)d_in[1];
  const float* Wk = (const float*)d_in[2];
  const float* Wv = (const float*)d_in[3];
  const float* Wo = (const float*)d_in[4];

  u16* qkv   = (u16*)d_ws;
  u16* vperm = qkv + (size_t)3 * 64 * 2048 * 64;
  u16* aout  = vperm + (size_t)64 * 64 * 2048;
  u16* xtok  = aout + (size_t)8192 * 1024;
  u16* xpos  = xtok + (size_t)8192 * 512;
  u16* Wt    = xpos + (size_t)8192 * 512;
  u16* WoT   = Wt + (size_t)3 * 1024 * 512;
  float* out = (float*)d_out;

  prep_x<<<dim3(8192), dim3(256), 0, stream>>>(x, xtok, xpos);
  prep_w<<<dim3(16, 16, 4), dim3(256), 0, stream>>>(Wq, Wk, Wv, Wo, Wt, WoT);
  gemm_qkv128<<<dim3(4, 64, 3), dim3(512), 0, stream>>>(xtok, xpos, Wt, qkv, vperm);
  attn<<<dim3(64, 16), dim3(256), 0, stream>>>(qkv, vperm, aout);
  gemm_out128<<<dim3(4, 64), dim3(512), 0, stream>>>(aout, WoT, out);
}

// Round 7
// 191.977 us; speedup vs baseline: 1.0854x; 1.0068x over previous
//
#include <hip/hip_runtime.h>
#include <stdint.h>

// SplitAttention: x->(x_tok|x_pos); Q=x_pos@Wq K=x_pos@Wk V=x_tok@Wv;
// causal 16-head attention (d=64); out = attn @ Wo. All MFMA bf16.
//
// R13: GEMM core rewritten 4-phase/dbuf -> TRIPLE-buffer, ONE phase per
// K-tile: {16 ds_read buf[t%3] || stage tile t+2 -> buf[(t+2)%3] (6 loads)
// -> barrier -> lgkmcnt(0) -> 32 MFMA -> vmcnt(6) -> barrier}. Halves
// barriers/K-tile, doubles MFMA burst, 2-tile prefetch depth, and removes
// R12's ph4 WAR race (staged buf is never the read buf; its last readers
// drained at the prior phase's lgkmcnt(0), one barrier earlier).
// LDS 144KB (3 x {A 16KB + B 32KB}). attn unchanged from R12 (46us best).

typedef unsigned short u16;
typedef __bf16 bf16;
typedef bf16 bf16x8 __attribute__((ext_vector_type(8)));
typedef u16 u16x8 __attribute__((ext_vector_type(8)));
typedef u16 u16x4 __attribute__((ext_vector_type(4)));
typedef float f32x4 __attribute__((ext_vector_type(4)));
typedef uint32_t u32x4 __attribute__((ext_vector_type(4)));

__device__ __forceinline__ u16 cvt_bf16(float f) {
  uint32_t u = __builtin_bit_cast(uint32_t, f);
  u += 0x7FFFu + ((u >> 16) & 1u);   // RNE
  return (u16)(u >> 16);
}

// pack two f32 -> (bf16 lo | bf16 hi) with +0.5ulp rounding, one v_perm_b32
__device__ __forceinline__ uint32_t pack2_bf16(float lo, float hi) {
  uint32_t a = __builtin_bit_cast(uint32_t, lo) + 0x8000u;
  uint32_t b = __builtin_bit_cast(uint32_t, hi) + 0x8000u;
  return __builtin_amdgcn_perm(b, a, 0x07060302u);
}

__device__ __forceinline__ f32x4 mfma_bf(bf16x8 a, bf16x8 b, f32x4 c) {
  return __builtin_amdgcn_mfma_f32_16x16x32_bf16(a, b, c, 0, 0, 0);
}

typedef __attribute__((address_space(1))) const uint32_t g_u32;
typedef __attribute__((address_space(3))) uint32_t l_u32;
__device__ __forceinline__ void gload16(const u16* g, u16* l) {
  __builtin_amdgcn_global_load_lds((g_u32*)g, (l_u32*)l, 16, 0, 0);
}

// ---------------- x -> bf16 tok/pos split
__global__ __launch_bounds__(256) void prep_x(
    const float* __restrict__ x, u16* __restrict__ xtok,
    u16* __restrict__ xpos) {
  int idx = blockIdx.x * 256 + threadIdx.x;
  int row = idx >> 8;
  int c4 = (idx & 255) * 4;
  float4 v = *(const float4*)(x + (size_t)row * 1024 + c4);
  u16x4 b = {cvt_bf16(v.x), cvt_bf16(v.y), cvt_bf16(v.z), cvt_bf16(v.w)};
  u16* dst = (c4 < 512) ? (xtok + (size_t)row * 512 + c4)
                        : (xpos + (size_t)row * 512 + c4 - 512);
  *(u16x4*)dst = b;
}

// ---------------- W[k][n] f32 -> Wt[n][k] bf16 (z=0..2: 512x1024; z=3: Wo 1024x1024)
__global__ __launch_bounds__(256) void prep_w(
    const float* __restrict__ Wq, const float* __restrict__ Wk,
    const float* __restrict__ Wv, const float* __restrict__ Wo,
    u16* __restrict__ Wt, u16* __restrict__ WoT) {
  const int z = blockIdx.z;
  const float* src = (z == 0) ? Wq : (z == 1) ? Wk : (z == 2) ? Wv : Wo;
  const int K = (z == 3) ? 1024 : 512;
  u16* dst = (z == 3) ? WoT : (Wt + (size_t)z * 1024 * 512);
  const int k0 = blockIdx.y * 64, n0 = blockIdx.x * 64;
  if (k0 >= K) return;
  __shared__ u16 T[64][68];
  const int tid = threadIdx.x;
  const int r = tid >> 4, c = (tid & 15) * 4;
#pragma unroll
  for (int i = 0; i < 4; i++) {
    float4 v = *(const float4*)(src + (size_t)(k0 + r + i * 16) * 1024 + n0 + c);
    u16x4 b = {cvt_bf16(v.x), cvt_bf16(v.y), cvt_bf16(v.z), cvt_bf16(v.w)};
    *(u16x4*)&T[r + i * 16][c] = b;
  }
  __syncthreads();
#pragma unroll
  for (int i = 0; i < 4; i++) {
    int n = r + i * 16;
    u16x4 v;
#pragma unroll
    for (int j = 0; j < 4; j++) v[j] = T[c + j][n];
    *(u16x4*)(dst + (size_t)(n0 + n) * K + k0 + c) = v;
  }
}

// ================= 128x256 triple-buffer GEMM core =================
// 512 threads = 8 waves (2M x 4N), per-wave C = 64x64, acc[4][4].
// LDS 144KB: A[3 buf][128][64] (48KB) + B[3 buf][2 half][128][64] (96KB).
// One phase per K-tile t: read buf[t%3] (16 ds_read_b128/wave), stage the
// full tile t+2 into buf[(t+2)%3] (6 gload_lds/thread), barrier,
// lgkmcnt(0), 32 MFMA, vmcnt(6) [= tile t+2's loads left in flight;
// oldest 6 = tile t+1 retired], barrier. WAR-safe by construction:
// staged buf != read buf, and staged buf's last readers (phase t-1)
// drained at that phase's lgkmcnt(0), one barrier before these gloads.
// 16B-slot XOR swizzle slot^=(row&7): pre-swizzled global source (linear
// LDS dest) + swizzled ds_read col offsets.

#define MM1(M_, N_, J_) { f32x4 c_ = acc[M_][N_];                            \
  c_ = mfma_bf(af[J_][0], bf[N_][0], c_);                                    \
  c_ = mfma_bf(af[J_][1], bf[N_][1], c_);                                    \
  acc[M_][N_] = c_; }

#define XMM(NB) MM1(0,(NB)+0,0) MM1(0,(NB)+1,0) MM1(1,(NB)+0,1)              \
                MM1(1,(NB)+1,1) MM1(2,(NB)+0,2) MM1(2,(NB)+1,2)              \
                MM1(3,(NB)+0,3) MM1(3,(NB)+1,3)

#define XLDA(P) { const u16* bp_ = rA + (P)*8192;                            \
  af[0][0] = *(const bf16x8*)(bp_ + 0*1024 + colx0);                         \
  af[0][1] = *(const bf16x8*)(bp_ + 0*1024 + colx1);                         \
  af[1][0] = *(const bf16x8*)(bp_ + 1*1024 + colx0);                         \
  af[1][1] = *(const bf16x8*)(bp_ + 1*1024 + colx1);                         \
  af[2][0] = *(const bf16x8*)(bp_ + 2*1024 + colx0);                         \
  af[2][1] = *(const bf16x8*)(bp_ + 2*1024 + colx1);                         \
  af[3][0] = *(const bf16x8*)(bp_ + 3*1024 + colx0);                         \
  af[3][1] = *(const bf16x8*)(bp_ + 3*1024 + colx1); }

#define XLDB(P, NB) { const u16* bp_ = rB + (P)*16384;                       \
  bf[(NB)+0][0] = *(const bf16x8*)(bp_ + ((NB)+0)*1024 + colx0);             \
  bf[(NB)+0][1] = *(const bf16x8*)(bp_ + ((NB)+0)*1024 + colx1);             \
  bf[(NB)+1][0] = *(const bf16x8*)(bp_ + ((NB)+1)*1024 + colx0);             \
  bf[(NB)+1][1] = *(const bf16x8*)(bp_ + ((NB)+1)*1024 + colx1); }

#define XSTA(P, KT) { const u16* s_ = gA + (KT)*64;                          \
  u16* d_ = lA + (P)*8192;                                                   \
  gload16(s_, d_); gload16(s_ + (size_t)64*Kd, d_ + 4096); }

#define XSTB0(P, KT) { const u16* s_ = gB + (KT)*64;                         \
  u16* d_ = lB + (P)*16384;                                                  \
  gload16(s_, d_); gload16(s_ + (size_t)64*Kd, d_ + 4096); }

#define XSTB1(P, KT) { const u16* s_ = gB + (size_t)128*Kd + (KT)*64;        \
  u16* d_ = lB + (P)*16384 + 8192;                                           \
  gload16(s_, d_); gload16(s_ + (size_t)64*Kd, d_ + 4096); }

#define PH_MID  asm volatile("" ::: "memory"); __builtin_amdgcn_s_barrier(); \
  asm volatile("s_waitcnt lgkmcnt(0)" ::: "memory");                         \
  __builtin_amdgcn_s_setprio(1);

#define PH_END_VM6  __builtin_amdgcn_s_setprio(0);                           \
  asm volatile("s_waitcnt vmcnt(6)" ::: "memory");                           \
  asm volatile("" ::: "memory"); __builtin_amdgcn_s_barrier();

template <int Kd>
__device__ __forceinline__ void gemm128_core(
    const u16* __restrict__ Aptr, const u16* __restrict__ Bptr,
    int m0, int n0, u16* smem, f32x4 (&acc)[4][4]) {
  constexpr int NKT = Kd / 64;
  const int tid = threadIdx.x;
  const int lane = tid & 63;
  const int mrow = lane & 15, quad = lane >> 4;
  const int w = tid >> 6, wm2 = w >> 2, wn4 = w & 3;

  u16* As = smem;                 // 3 x 8192 u16
  u16* Bs = smem + 24576;         // 3 x 16384 u16

  // staging: thread -> (row = tid>>3 (+64 second load), 16B slot = tid&7)
  const int lrs = tid >> 3, sp8 = tid & 7;
  const int slog = sp8 ^ (lrs & 7);          // pre-swizzled global slot
  const u16* gA = Aptr + (size_t)(m0 + lrs) * Kd + slog * 8;
  const u16* gB = Bptr + (size_t)(n0 + lrs) * Kd + slog * 8;
  u16* lA = As + tid * 8;
  u16* lB = Bs + tid * 8;

  // reads: swizzled column offsets (u16 units), key = (mrow&7)*8
  const int colx0 = (quad * 8) ^ ((mrow & 7) * 8);
  const int colx1 = (32 + quad * 8) ^ ((mrow & 7) * 8);
  const u16* rA = As + (wm2 * 64 + mrow) * 64;
  const u16* rB = Bs + (wn4 >> 1) * 8192 + ((wn4 & 1) * 64 + mrow) * 64;

  bf16x8 af[4][2], bf[4][2];

  // prologue: stage tiles 0 (buf0) and 1 (buf1); gate tile 0 -> vmcnt(6)
  XSTA(0, 0) XSTB0(0, 0) XSTB1(0, 0)
  XSTA(1, 1) XSTB0(1, 1) XSTB1(1, 1)
  asm volatile("s_waitcnt vmcnt(6)" ::: "memory");
  asm volatile("" ::: "memory");
  __builtin_amdgcn_s_barrier();

  int p = 0, ps = 2;
  for (int t = 0; t < NKT; ++t) {
    const int kt = (t + 2 < NKT) ? t + 2 : NKT - 1;  // clamp keeps vmcnt uniform
    XLDA(p) XLDB(p, 0) XLDB(p, 2)
    XSTA(ps, kt) XSTB0(ps, kt) XSTB1(ps, kt)
    PH_MID
    XMM(0) XMM(2)
    PH_END_VM6
    p = (p == 2) ? 0 : p + 1;
    ps = (ps == 2) ? 0 : ps + 1;
  }
  asm volatile("s_waitcnt vmcnt(0)" ::: "memory");  // drain tail stages
  __builtin_amdgcn_s_barrier();
}

// XCD-aware remap (bijective, nwg = 4*64 = 256, 256%8 == 0): slots on one
// XCD get consecutive work-ids -> A-panel shared in-XCD, B L2-resident.
__device__ __forceinline__ void xcd_remap(int& bx, int& by) {
  int flat = blockIdx.x + 4 * blockIdx.y;
  int wg = (flat & 7) * 32 + (flat >> 3);
  bx = wg & 3;
  by = wg >> 2;
}

// ---------------- QKV projection, 128x256 triple-buffer
__global__ __launch_bounds__(512, 1) void gemm_qkv128(
    const u16* __restrict__ xtok, const u16* __restrict__ xpos,
    const u16* __restrict__ Wt, u16* __restrict__ qkv,
    u16* __restrict__ vperm) {
  const int z = blockIdx.z;
  const u16* A = (z == 2) ? xtok : xpos;
  const u16* Bt = Wt + (size_t)z * 1024 * 512;
  u16* outp = qkv + (size_t)z * (64u * 2048u * 64u);
  const float osc = (z == 0) ? 0.18033688011112042f : 1.0f;  // 0.125*log2e
  int bx, by;
  xcd_remap(bx, by);
  const int m0 = by * 128, n0 = bx * 256;

  __shared__ __align__(16) u16 smem[73728];
  f32x4 acc[4][4];
#pragma unroll
  for (int i = 0; i < 4; i++)
#pragma unroll
    for (int j = 0; j < 4; j++) acc[i][j] = (f32x4){0.f, 0.f, 0.f, 0.f};

  gemm128_core<512>(A, Bt, m0, n0, smem, acc);

  const int tid = threadIdx.x;
  const int lane = tid & 63;
  const int mrow = lane & 15, quad = lane >> 4;
  const int w = tid >> 6, wm2 = w >> 2, wn4 = w & 3;

  if (z != 2) {
#pragma unroll
    for (int mi = 0; mi < 4; mi++)
#pragma unroll
      for (int ni = 0; ni < 4; ni++)
#pragma unroll
        for (int r = 0; r < 4; r++) {
          int m = m0 + wm2 * 64 + mi * 16 + quad * 4 + r;
          int n = n0 + wn4 * 64 + ni * 16 + mrow;
          int bb = m >> 11, t = m & 2047;
          int h = n >> 6, d = n & 63;
          outp[(((size_t)(bb * 16 + h)) * 2048 + t) * 64 + d] =
              cvt_bf16(acc[mi][ni][r] * osc);
        }
  } else {
#pragma unroll
    for (int mi = 0; mi < 4; mi++)
#pragma unroll
      for (int ni = 0; ni < 4; ni++)
#pragma unroll
        for (int r = 0; r < 4; r++) {
          int m = m0 + wm2 * 64 + mi * 16 + quad * 4 + r;
          int n = n0 + wn4 * 64 + ni * 16 + mrow;
          int bb = m >> 11, t = m & 2047;
          int h = n >> 6, d = n & 63;
          int k6 = t & 63;
          int pos = (k6 & 32) + ((k6 >> 4) & 1) * 4 + ((k6 >> 2) & 3) * 8 +
                    (k6 & 3);
          vperm[(((size_t)(bb * 16 + h)) * 64 + d) * 2048 + (t & ~63) + pos] =
              cvt_bf16(acc[mi][ni][r]);
        }
  }
}

// ---------------- Output projection, 128x256 triple-buffer: aout @ WoT -> f32
__global__ __launch_bounds__(512, 1) void gemm_out128(
    const u16* __restrict__ Am, const u16* __restrict__ WoT,
    float* __restrict__ out) {
  int bx, by;
  xcd_remap(bx, by);
  const int m0 = by * 128, n0 = bx * 256;

  __shared__ __align__(16) u16 smem[73728];
  f32x4 acc[4][4];
#pragma unroll
  for (int i = 0; i < 4; i++)
#pragma unroll
    for (int j = 0; j < 4; j++) acc[i][j] = (f32x4){0.f, 0.f, 0.f, 0.f};

  gemm128_core<1024>(Am, WoT, m0, n0, smem, acc);

  const int tid = threadIdx.x;
  const int lane = tid & 63;
  const int mrow = lane & 15, quad = lane >> 4;
  const int w = tid >> 6, wm2 = w >> 2, wn4 = w & 3;

#pragma unroll
  for (int mi = 0; mi < 4; mi++)
#pragma unroll
    for (int ni = 0; ni < 4; ni++)
#pragma unroll
      for (int r = 0; r < 4; r++) {
        int m = m0 + wm2 * 64 + mi * 16 + quad * 4 + r;
        int n = n0 + wn4 * 64 + ni * 16 + mrow;
        out[(size_t)m * 1024 + n] = acc[mi][ni][r];
      }
}

// ---------------- Flash attention (S^T / O^T, no max, 128-row q-tiles)
// R10/R12 structure (best measured): one 128-row q-tile per block, grid
// (64,16), longest-first (qt = 15-by). 2 q-groups of 16 rows per wave.
// K/V LDS double-buffered, ONE __syncthreads per k-iter; register
// prefetch issued before the barrier. launch_bounds(256,3): floor 3
// waves/EU, cap 170 VGPR -> natural 72 VGPR, no spill (verified R6).
__global__ __launch_bounds__(256, 3) void attn(
    const u16* __restrict__ qkv, const u16* __restrict__ vperm,
    u16* __restrict__ aout) {
  const int bh = blockIdx.x;
  const int qt = 15 - blockIdx.y;   // 128-row q-tile, longest first
  const int bb = bh >> 4, h = bh & 15;
  const u16* Qp = qkv + (size_t)bh * (2048 * 64);
  const u16* Kp = qkv + (size_t)(64 + bh) * (2048 * 64);
  const u16* Vp = vperm + (size_t)bh * (64 * 2048);

  // [buf][section: K0,K1,V0,V1][64*32]
  __shared__ __align__(16) u16 smem[2][4][64 * 32];

  const int tid = threadIdx.x;
  const int lane = tid & 63;
  const int w = tid >> 6;
  const int mrow = lane & 15;
  const int quad = lane >> 4;
  const int srow = w * 16 + (lane >> 2);
  const int sc = (lane & 3) * 8;
  const int soff = srow * 32 + sc;

  const u16x8 onesu = {0x3F80, 0x3F80, 0x3F80, 0x3F80,
                       0x3F80, 0x3F80, 0x3F80, 0x3F80};
  const bf16x8 ones = __builtin_bit_cast(bf16x8, onesu);

  const u16* kgb = Kp + (size_t)srow * 64 + sc;   // + k0*64 per tile
  const u16* vgb = Vp + (size_t)srow * 2048 + sc; // + k0 per tile

  const int q0 = qt * 128;
  const int nk = 2 * qt + 2;
  const int qw = q0 + w * 32;                  // wave's first q row

  const u16* qbase = Qp + (size_t)(qw + mrow) * 64 + quad * 8;
  const bf16x8 qf00 = *(const bf16x8*)qbase;             // g=0, d 0..31
  const bf16x8 qf01 = *(const bf16x8*)(qbase + 32);      // g=0, d 32..63
  const bf16x8 qf10 = *(const bf16x8*)(qbase + 16 * 64);       // g=1
  const bf16x8 qf11 = *(const bf16x8*)(qbase + 16 * 64 + 32);  // g=1

  f32x4 o[2][4], ol[2];
#pragma unroll
  for (int g = 0; g < 2; ++g) {
#pragma unroll
    for (int dt = 0; dt < 4; ++dt) o[g][dt] = (f32x4){0.f, 0.f, 0.f, 0.f};
    ol[g] = (f32x4){0.f, 0.f, 0.f, 0.f};
  }

  // prefetch tile 0
  u16x8 ka0 = *(const u16x8*)kgb;
  u16x8 ka1 = *(const u16x8*)(kgb + 32);
  u16x8 va0 = *(const u16x8*)vgb;
  u16x8 va1 = *(const u16x8*)(vgb + 32);

  for (int it = 0; it < nk; ++it) {
    u16* buf = &smem[it & 1][0][0];
    *(u16x8*)(buf + 0 * 2048 + soff) = ka0;
    *(u16x8*)(buf + 1 * 2048 + soff) = ka1;
    *(u16x8*)(buf + 2 * 2048 + soff) = va0;
    *(u16x8*)(buf + 3 * 2048 + soff) = va1;

    if (it + 1 < nk) {   // issue next tile's loads; land during compute
      const int kn = (it + 1) * 64;
      ka0 = *(const u16x8*)(kgb + (size_t)kn * 64);
      ka1 = *(const u16x8*)(kgb + (size_t)kn * 64 + 32);
      va0 = *(const u16x8*)(vgb + kn);
      va1 = *(const u16x8*)(vgb + kn + 32);
    }

    __syncthreads();   // buf[it&1] visible; prior readers done at barrier it-1

    const int k0 = it * 64;
    if (k0 > qw + 31) continue;   // tile entirely above causal diagonal

    // S^T = K · Q^T  (C: row = key-in-tile = quad*4+r, col = q = mrow)
    f32x4 s[2][4];
#pragma unroll
    for (int nt = 0; nt < 4; ++nt) {
      bf16x8 kf0 = *(const bf16x8*)(buf + 0 * 2048 + (nt * 16 + mrow) * 32 + quad * 8);
      bf16x8 kf1 = *(const bf16x8*)(buf + 1 * 2048 + (nt * 16 + mrow) * 32 + quad * 8);
      f32x4 z0 = (f32x4){0.f, 0.f, 0.f, 0.f};
      z0 = mfma_bf(kf0, qf00, z0);
      s[0][nt] = mfma_bf(kf1, qf01, z0);
      f32x4 z1 = (f32x4){0.f, 0.f, 0.f, 0.f};
      z1 = mfma_bf(kf0, qf10, z1);
      s[1][nt] = mfma_bf(kf1, qf11, z1);
    }

    if (k0 + 63 > qw) {   // diagonal tile for this wave: causal mask
#pragma unroll
      for (int g = 0; g < 2; ++g)
#pragma unroll
        for (int nt = 0; nt < 4; ++nt)
#pragma unroll
          for (int r = 0; r < 4; ++r)
            if (k0 + nt * 16 + quad * 4 + r > qw + g * 16 + mrow)
              s[g][nt][r] = -1e30f;
    }
    // p = exp2(s), no max subtraction (|s| bounded << 127)
#pragma unroll
    for (int g = 0; g < 2; ++g)
#pragma unroll
      for (int nt = 0; nt < 4; ++nt)
#pragma unroll
        for (int r = 0; r < 4; ++r)
          s[g][nt][r] = __builtin_amdgcn_exp2f(s[g][nt][r]);

    // P^T B-frags packed from s[] via v_perm
    bf16x8 pf[2][2];
#pragma unroll
    for (int g = 0; g < 2; ++g) {
      u32x4 pw0 = {pack2_bf16(s[g][0][0], s[g][0][1]),
                   pack2_bf16(s[g][0][2], s[g][0][3]),
                   pack2_bf16(s[g][1][0], s[g][1][1]),
                   pack2_bf16(s[g][1][2], s[g][1][3])};
      u32x4 pw1 = {pack2_bf16(s[g][2][0], s[g][2][1]),
                   pack2_bf16(s[g][2][2], s[g][2][3]),
                   pack2_bf16(s[g][3][0], s[g][3][1]),
                   pack2_bf16(s[g][3][2], s[g][3][3])};
      pf[g][0] = __builtin_bit_cast(bf16x8, pw0);
      pf[g][1] = __builtin_bit_cast(bf16x8, pw1);
      // l row-sum via ones A-frag
      ol[g] = mfma_bf(ones, pf[g][0], ol[g]);
      ol[g] = mfma_bf(ones, pf[g][1], ol[g]);
    }

    // O^T += V^T · P^T  (each vf read feeds both q-groups)
#pragma unroll
    for (int dt = 0; dt < 4; ++dt) {
      bf16x8 vf0 = *(const bf16x8*)(buf + 2 * 2048 + (dt * 16 + mrow) * 32 + quad * 8);
      bf16x8 vf1 = *(const bf16x8*)(buf + 3 * 2048 + (dt * 16 + mrow) * 32 + quad * 8);
      o[0][dt] = mfma_bf(vf0, pf[0][0], o[0][dt]);
      o[0][dt] = mfma_bf(vf1, pf[0][1], o[0][dt]);
      o[1][dt] = mfma_bf(vf0, pf[1][0], o[1][dt]);
      o[1][dt] = mfma_bf(vf1, pf[1][1], o[1][dt]);
    }
  }

  __syncthreads();   // all K/V readers done; reuse smem as Osh[4][32][72]
  u16* Osh = &smem[0][0][0];

  // epilogue: normalize, transpose O^T -> O through per-wave LDS, store
#pragma unroll
  for (int g = 0; g < 2; ++g) {
    const float inv = 1.f / ol[g][0];
#pragma unroll
    for (int dt = 0; dt < 4; ++dt)
#pragma unroll
      for (int r = 0; r < 4; ++r)
        Osh[(w * 32 + g * 16 + mrow) * 72 + dt * 16 + quad * 4 + r] =
            cvt_bf16(o[g][dt][r] * inv);
  }
#pragma unroll
  for (int p = 0; p < 4; ++p) {
    int ql = (lane >> 3) + 8 * p;
    int ch = lane & 7;
    u16x8 v = *(const u16x8*)&Osh[(w * 32 + ql) * 72 + ch * 8];
    int t = q0 + w * 32 + ql;
    *(u16x8*)(aout + ((size_t)(bb * 2048 + t)) * 1024 + h * 64 + ch * 8) = v;
  }
}

extern "C" void kernel_launch(void* const* d_in, const int* in_sizes, int n_in,
                              void* d_out, int out_size, void* d_ws, size_t ws_size,
                              hipStream_t stream) {
  const float* x  = (const float*)d_in[0];
  const float* Wq = (const float*)d_in[1];
  const float* Wk = (const float*)d_in[2];
  const float* Wv = (const float*)d_in[3];
  const float* Wo = (const float*)d_in[4];

  u16* qkv   = (u16*)d_ws;
  u16* vperm = qkv + (size_t)3 * 64 * 2048 * 64;
  u16* aout  = vperm + (size_t)64 * 64 * 2048;
  u16* xtok  = aout + (size_t)8192 * 1024;
  u16* xpos  = xtok + (size_t)8192 * 512;
  u16* Wt    = xpos + (size_t)8192 * 512;
  u16* WoT   = Wt + (size_t)3 * 1024 * 512;
  float* out = (float*)d_out;

  prep_x<<<dim3(8192), dim3(256), 0, stream>>>(x, xtok, xpos);
  prep_w<<<dim3(16, 16, 4), dim3(256), 0, stream>>>(Wq, Wk, Wv, Wo, Wt, WoT);
  gemm_qkv128<<<dim3(4, 64, 3), dim3(512), 0, stream>>>(xtok, xpos, Wt, qkv, vperm);
  attn<<<dim3(64, 16), dim3(256), 0, stream>>>(qkv, vperm, aout);
  gemm_out128<<<dim3(4, 64), dim3(512), 0, stream>>>(aout, WoT, out);
}

// Round 8
// 188.709 us; speedup vs baseline: 1.1042x; 1.0173x over previous
//
#include <hip/hip_runtime.h>
#include <stdint.h>

// SplitAttention: x->(x_tok|x_pos); Q=x_pos@Wq K=x_pos@Wk V=x_tok@Wv;
// causal 16-head attention (d=64); out = attn @ Wo. All MFMA bf16.
//
// R14: (1) prep_x+prep_w merged into ONE flat-grid kernel (5->4 dispatches;
// budget audit shows ~60-90us of e2e is not in any dispatch -> launch
// overhead suspect). (2) attn P-frag packing via compiler bf16 casts
// (pairs into v_cvt_pk_bf16_f32; -32 VALU/iter vs perm+add; RNE). GEMMs
// unchanged (R13 triple-buffer 128x256).

typedef unsigned short u16;
typedef __bf16 bf16;
typedef bf16 bf16x8 __attribute__((ext_vector_type(8)));
typedef u16 u16x8 __attribute__((ext_vector_type(8)));
typedef u16 u16x4 __attribute__((ext_vector_type(4)));
typedef float f32x4 __attribute__((ext_vector_type(4)));
typedef uint32_t u32x4 __attribute__((ext_vector_type(4)));

__device__ __forceinline__ u16 cvt_bf16(float f) {
  uint32_t u = __builtin_bit_cast(uint32_t, f);
  u += 0x7FFFu + ((u >> 16) & 1u);   // RNE
  return (u16)(u >> 16);
}

__device__ __forceinline__ f32x4 mfma_bf(bf16x8 a, bf16x8 b, f32x4 c) {
  return __builtin_amdgcn_mfma_f32_16x16x32_bf16(a, b, c, 0, 0, 0);
}

typedef __attribute__((address_space(1))) const uint32_t g_u32;
typedef __attribute__((address_space(3))) uint32_t l_u32;
__device__ __forceinline__ void gload16(const u16* g, u16* l) {
  __builtin_amdgcn_global_load_lds((g_u32*)g, (l_u32*)l, 16, 0, 0);
}

// ---------------- merged prep: gid<1024 -> W[k][n] f32 -> Wt[n][k] bf16
// (z=0..2: 512x1024; z=3: Wo 1024x1024); gid>=1024 -> x -> tok/pos split.
__global__ __launch_bounds__(256) void prep(
    const float* __restrict__ x, const float* __restrict__ Wq,
    const float* __restrict__ Wk, const float* __restrict__ Wv,
    const float* __restrict__ Wo, u16* __restrict__ xtok,
    u16* __restrict__ xpos, u16* __restrict__ Wt, u16* __restrict__ WoT) {
  const int gid = blockIdx.x;
  const int tid = threadIdx.x;
  if (gid < 1024) {
    const int z = gid >> 8;
    const float* src = (z == 0) ? Wq : (z == 1) ? Wk : (z == 2) ? Wv : Wo;
    const int K = (z == 3) ? 1024 : 512;
    u16* dst = (z == 3) ? WoT : (Wt + (size_t)z * 1024 * 512);
    const int k0 = ((gid >> 4) & 15) * 64, n0 = (gid & 15) * 64;
    if (k0 >= K) return;
    __shared__ u16 T[64][68];
    const int r = tid >> 4, c = (tid & 15) * 4;
#pragma unroll
    for (int i = 0; i < 4; i++) {
      float4 v = *(const float4*)(src + (size_t)(k0 + r + i * 16) * 1024 + n0 + c);
      u16x4 b = {cvt_bf16(v.x), cvt_bf16(v.y), cvt_bf16(v.z), cvt_bf16(v.w)};
      *(u16x4*)&T[r + i * 16][c] = b;
    }
    __syncthreads();
#pragma unroll
    for (int i = 0; i < 4; i++) {
      int n = r + i * 16;
      u16x4 v;
#pragma unroll
      for (int j = 0; j < 4; j++) v[j] = T[c + j][n];
      *(u16x4*)(dst + (size_t)(n0 + n) * K + k0 + c) = v;
    }
  } else {
    int idx = (gid - 1024) * 256 + tid;
    int row = idx >> 8;
    int c4 = (idx & 255) * 4;
    float4 v = *(const float4*)(x + (size_t)row * 1024 + c4);
    u16x4 b = {cvt_bf16(v.x), cvt_bf16(v.y), cvt_bf16(v.z), cvt_bf16(v.w)};
    u16* dst = (c4 < 512) ? (xtok + (size_t)row * 512 + c4)
                          : (xpos + (size_t)row * 512 + c4 - 512);
    *(u16x4*)dst = b;
  }
}

// ================= 128x256 triple-buffer GEMM core =================
// 512 threads = 8 waves (2M x 4N), per-wave C = 64x64, acc[4][4].
// LDS 144KB: A[3 buf][128][64] (48KB) + B[3 buf][2 half][128][64] (96KB).
// One phase per K-tile t: read buf[t%3] (16 ds_read_b128/wave), stage the
// full tile t+2 into buf[(t+2)%3] (6 gload_lds/thread), barrier,
// lgkmcnt(0), 32 MFMA, vmcnt(6), barrier. WAR-safe: staged buf != read
// buf; staged buf's last readers drained one barrier earlier.
// 16B-slot XOR swizzle slot^=(row&7) on global source + ds_read cols.

#define MM1(M_, N_, J_) { f32x4 c_ = acc[M_][N_];                            \
  c_ = mfma_bf(af[J_][0], bf[N_][0], c_);                                    \
  c_ = mfma_bf(af[J_][1], bf[N_][1], c_);                                    \
  acc[M_][N_] = c_; }

#define XMM(NB) MM1(0,(NB)+0,0) MM1(0,(NB)+1,0) MM1(1,(NB)+0,1)              \
                MM1(1,(NB)+1,1) MM1(2,(NB)+0,2) MM1(2,(NB)+1,2)              \
                MM1(3,(NB)+0,3) MM1(3,(NB)+1,3)

#define XLDA(P) { const u16* bp_ = rA + (P)*8192;                            \
  af[0][0] = *(const bf16x8*)(bp_ + 0*1024 + colx0);                         \
  af[0][1] = *(const bf16x8*)(bp_ + 0*1024 + colx1);                         \
  af[1][0] = *(const bf16x8*)(bp_ + 1*1024 + colx0);                         \
  af[1][1] = *(const bf16x8*)(bp_ + 1*1024 + colx1);                         \
  af[2][0] = *(const bf16x8*)(bp_ + 2*1024 + colx0);                         \
  af[2][1] = *(const bf16x8*)(bp_ + 2*1024 + colx1);                         \
  af[3][0] = *(const bf16x8*)(bp_ + 3*1024 + colx0);                         \
  af[3][1] = *(const bf16x8*)(bp_ + 3*1024 + colx1); }

#define XLDB(P, NB) { const u16* bp_ = rB + (P)*16384;                       \
  bf[(NB)+0][0] = *(const bf16x8*)(bp_ + ((NB)+0)*1024 + colx0);             \
  bf[(NB)+0][1] = *(const bf16x8*)(bp_ + ((NB)+0)*1024 + colx1);             \
  bf[(NB)+1][0] = *(const bf16x8*)(bp_ + ((NB)+1)*1024 + colx0);             \
  bf[(NB)+1][1] = *(const bf16x8*)(bp_ + ((NB)+1)*1024 + colx1); }

#define XSTA(P, KT) { const u16* s_ = gA + (KT)*64;                          \
  u16* d_ = lA + (P)*8192;                                                   \
  gload16(s_, d_); gload16(s_ + (size_t)64*Kd, d_ + 4096); }

#define XSTB0(P, KT) { const u16* s_ = gB + (KT)*64;                         \
  u16* d_ = lB + (P)*16384;                                                  \
  gload16(s_, d_); gload16(s_ + (size_t)64*Kd, d_ + 4096); }

#define XSTB1(P, KT) { const u16* s_ = gB + (size_t)128*Kd + (KT)*64;        \
  u16* d_ = lB + (P)*16384 + 8192;                                           \
  gload16(s_, d_); gload16(s_ + (size_t)64*Kd, d_ + 4096); }

#define PH_MID  asm volatile("" ::: "memory"); __builtin_amdgcn_s_barrier(); \
  asm volatile("s_waitcnt lgkmcnt(0)" ::: "memory");                         \
  __builtin_amdgcn_s_setprio(1);

#define PH_END_VM6  __builtin_amdgcn_s_setprio(0);                           \
  asm volatile("s_waitcnt vmcnt(6)" ::: "memory");                           \
  asm volatile("" ::: "memory"); __builtin_amdgcn_s_barrier();

template <int Kd>
__device__ __forceinline__ void gemm128_core(
    const u16* __restrict__ Aptr, const u16* __restrict__ Bptr,
    int m0, int n0, u16* smem, f32x4 (&acc)[4][4]) {
  constexpr int NKT = Kd / 64;
  const int tid = threadIdx.x;
  const int lane = tid & 63;
  const int mrow = lane & 15, quad = lane >> 4;
  const int w = tid >> 6, wm2 = w >> 2, wn4 = w & 3;

  u16* As = smem;                 // 3 x 8192 u16
  u16* Bs = smem + 24576;         // 3 x 16384 u16

  // staging: thread -> (row = tid>>3 (+64 second load), 16B slot = tid&7)
  const int lrs = tid >> 3, sp8 = tid & 7;
  const int slog = sp8 ^ (lrs & 7);          // pre-swizzled global slot
  const u16* gA = Aptr + (size_t)(m0 + lrs) * Kd + slog * 8;
  const u16* gB = Bptr + (size_t)(n0 + lrs) * Kd + slog * 8;
  u16* lA = As + tid * 8;
  u16* lB = Bs + tid * 8;

  // reads: swizzled column offsets (u16 units), key = (mrow&7)*8
  const int colx0 = (quad * 8) ^ ((mrow & 7) * 8);
  const int colx1 = (32 + quad * 8) ^ ((mrow & 7) * 8);
  const u16* rA = As + (wm2 * 64 + mrow) * 64;
  const u16* rB = Bs + (wn4 >> 1) * 8192 + ((wn4 & 1) * 64 + mrow) * 64;

  bf16x8 af[4][2], bf[4][2];

  // prologue: stage tiles 0 (buf0) and 1 (buf1); gate tile 0 -> vmcnt(6)
  XSTA(0, 0) XSTB0(0, 0) XSTB1(0, 0)
  XSTA(1, 1) XSTB0(1, 1) XSTB1(1, 1)
  asm volatile("s_waitcnt vmcnt(6)" ::: "memory");
  asm volatile("" ::: "memory");
  __builtin_amdgcn_s_barrier();

  int p = 0, ps = 2;
  for (int t = 0; t < NKT; ++t) {
    const int kt = (t + 2 < NKT) ? t + 2 : NKT - 1;  // clamp keeps vmcnt uniform
    XLDA(p) XLDB(p, 0) XLDB(p, 2)
    XSTA(ps, kt) XSTB0(ps, kt) XSTB1(ps, kt)
    PH_MID
    XMM(0) XMM(2)
    PH_END_VM6
    p = (p == 2) ? 0 : p + 1;
    ps = (ps == 2) ? 0 : ps + 1;
  }
  asm volatile("s_waitcnt vmcnt(0)" ::: "memory");  // drain tail stages
  __builtin_amdgcn_s_barrier();
}

// XCD-aware remap (bijective, nwg = 4*64 = 256, 256%8 == 0): slots on one
// XCD get consecutive work-ids -> A-panel shared in-XCD, B L2-resident.
__device__ __forceinline__ void xcd_remap(int& bx, int& by) {
  int flat = blockIdx.x + 4 * blockIdx.y;
  int wg = (flat & 7) * 32 + (flat >> 3);
  bx = wg & 3;
  by = wg >> 2;
}

// ---------------- QKV projection, 128x256 triple-buffer
__global__ __launch_bounds__(512, 1) void gemm_qkv128(
    const u16* __restrict__ xtok, const u16* __restrict__ xpos,
    const u16* __restrict__ Wt, u16* __restrict__ qkv,
    u16* __restrict__ vperm) {
  const int z = blockIdx.z;
  const u16* A = (z == 2) ? xtok : xpos;
  const u16* Bt = Wt + (size_t)z * 1024 * 512;
  u16* outp = qkv + (size_t)z * (64u * 2048u * 64u);
  const float osc = (z == 0) ? 0.18033688011112042f : 1.0f;  // 0.125*log2e
  int bx, by;
  xcd_remap(bx, by);
  const int m0 = by * 128, n0 = bx * 256;

  __shared__ __align__(16) u16 smem[73728];
  f32x4 acc[4][4];
#pragma unroll
  for (int i = 0; i < 4; i++)
#pragma unroll
    for (int j = 0; j < 4; j++) acc[i][j] = (f32x4){0.f, 0.f, 0.f, 0.f};

  gemm128_core<512>(A, Bt, m0, n0, smem, acc);

  const int tid = threadIdx.x;
  const int lane = tid & 63;
  const int mrow = lane & 15, quad = lane >> 4;
  const int w = tid >> 6, wm2 = w >> 2, wn4 = w & 3;

  if (z != 2) {
#pragma unroll
    for (int mi = 0; mi < 4; mi++)
#pragma unroll
      for (int ni = 0; ni < 4; ni++)
#pragma unroll
        for (int r = 0; r < 4; r++) {
          int m = m0 + wm2 * 64 + mi * 16 + quad * 4 + r;
          int n = n0 + wn4 * 64 + ni * 16 + mrow;
          int bb = m >> 11, t = m & 2047;
          int h = n >> 6, d = n & 63;
          outp[(((size_t)(bb * 16 + h)) * 2048 + t) * 64 + d] =
              cvt_bf16(acc[mi][ni][r] * osc);
        }
  } else {
#pragma unroll
    for (int mi = 0; mi < 4; mi++)
#pragma unroll
      for (int ni = 0; ni < 4; ni++)
#pragma unroll
        for (int r = 0; r < 4; r++) {
          int m = m0 + wm2 * 64 + mi * 16 + quad * 4 + r;
          int n = n0 + wn4 * 64 + ni * 16 + mrow;
          int bb = m >> 11, t = m & 2047;
          int h = n >> 6, d = n & 63;
          int k6 = t & 63;
          int pos = (k6 & 32) + ((k6 >> 4) & 1) * 4 + ((k6 >> 2) & 3) * 8 +
                    (k6 & 3);
          vperm[(((size_t)(bb * 16 + h)) * 64 + d) * 2048 + (t & ~63) + pos] =
              cvt_bf16(acc[mi][ni][r]);
        }
  }
}

// ---------------- Output projection, 128x256 triple-buffer: aout @ WoT -> f32
__global__ __launch_bounds__(512, 1) void gemm_out128(
    const u16* __restrict__ Am, const u16* __restrict__ WoT,
    float* __restrict__ out) {
  int bx, by;
  xcd_remap(bx, by);
  const int m0 = by * 128, n0 = bx * 256;

  __shared__ __align__(16) u16 smem[73728];
  f32x4 acc[4][4];
#pragma unroll
  for (int i = 0; i < 4; i++)
#pragma unroll
    for (int j = 0; j < 4; j++) acc[i][j] = (f32x4){0.f, 0.f, 0.f, 0.f};

  gemm128_core<1024>(Am, WoT, m0, n0, smem, acc);

  const int tid = threadIdx.x;
  const int lane = tid & 63;
  const int mrow = lane & 15, quad = lane >> 4;
  const int w = tid >> 6, wm2 = w >> 2, wn4 = w & 3;

#pragma unroll
  for (int mi = 0; mi < 4; mi++)
#pragma unroll
    for (int ni = 0; ni < 4; ni++)
#pragma unroll
      for (int r = 0; r < 4; r++) {
        int m = m0 + wm2 * 64 + mi * 16 + quad * 4 + r;
        int n = n0 + wn4 * 64 + ni * 16 + mrow;
        out[(size_t)m * 1024 + n] = acc[mi][ni][r];
      }
}

// ---------------- Flash attention (S^T / O^T, no max, 128-row q-tiles)
// R10/R12 structure: one 128-row q-tile per block, grid (64,16),
// longest-first (qt = 15-by). 2 q-groups of 16 rows per wave. K/V LDS
// double-buffered, ONE __syncthreads per k-iter; register prefetch
// issued before the barrier. launch_bounds(256,3) -> 72 VGPR, no spill.
// P-frag packing via compiler bf16 casts (pairs to v_cvt_pk_bf16_f32).
__global__ __launch_bounds__(256, 3) void attn(
    const u16* __restrict__ qkv, const u16* __restrict__ vperm,
    u16* __restrict__ aout) {
  const int bh = blockIdx.x;
  const int qt = 15 - blockIdx.y;   // 128-row q-tile, longest first
  const int bb = bh >> 4, h = bh & 15;
  const u16* Qp = qkv + (size_t)bh * (2048 * 64);
  const u16* Kp = qkv + (size_t)(64 + bh) * (2048 * 64);
  const u16* Vp = vperm + (size_t)bh * (64 * 2048);

  // [buf][section: K0,K1,V0,V1][64*32]
  __shared__ __align__(16) u16 smem[2][4][64 * 32];

  const int tid = threadIdx.x;
  const int lane = tid & 63;
  const int w = tid >> 6;
  const int mrow = lane & 15;
  const int quad = lane >> 4;
  const int srow = w * 16 + (lane >> 2);
  const int sc = (lane & 3) * 8;
  const int soff = srow * 32 + sc;

  const u16x8 onesu = {0x3F80, 0x3F80, 0x3F80, 0x3F80,
                       0x3F80, 0x3F80, 0x3F80, 0x3F80};
  const bf16x8 ones = __builtin_bit_cast(bf16x8, onesu);

  const u16* kgb = Kp + (size_t)srow * 64 + sc;   // + k0*64 per tile
  const u16* vgb = Vp + (size_t)srow * 2048 + sc; // + k0 per tile

  const int q0 = qt * 128;
  const int nk = 2 * qt + 2;
  const int qw = q0 + w * 32;                  // wave's first q row

  const u16* qbase = Qp + (size_t)(qw + mrow) * 64 + quad * 8;
  const bf16x8 qf00 = *(const bf16x8*)qbase;             // g=0, d 0..31
  const bf16x8 qf01 = *(const bf16x8*)(qbase + 32);      // g=0, d 32..63
  const bf16x8 qf10 = *(const bf16x8*)(qbase + 16 * 64);       // g=1
  const bf16x8 qf11 = *(const bf16x8*)(qbase + 16 * 64 + 32);  // g=1

  f32x4 o[2][4], ol[2];
#pragma unroll
  for (int g = 0; g < 2; ++g) {
#pragma unroll
    for (int dt = 0; dt < 4; ++dt) o[g][dt] = (f32x4){0.f, 0.f, 0.f, 0.f};
    ol[g] = (f32x4){0.f, 0.f, 0.f, 0.f};
  }

  // prefetch tile 0
  u16x8 ka0 = *(const u16x8*)kgb;
  u16x8 ka1 = *(const u16x8*)(kgb + 32);
  u16x8 va0 = *(const u16x8*)vgb;
  u16x8 va1 = *(const u16x8*)(vgb + 32);

  for (int it = 0; it < nk; ++it) {
    u16* buf = &smem[it & 1][0][0];
    *(u16x8*)(buf + 0 * 2048 + soff) = ka0;
    *(u16x8*)(buf + 1 * 2048 + soff) = ka1;
    *(u16x8*)(buf + 2 * 2048 + soff) = va0;
    *(u16x8*)(buf + 3 * 2048 + soff) = va1;

    if (it + 1 < nk) {   // issue next tile's loads; land during compute
      const int kn = (it + 1) * 64;
      ka0 = *(const u16x8*)(kgb + (size_t)kn * 64);
      ka1 = *(const u16x8*)(kgb + (size_t)kn * 64 + 32);
      va0 = *(const u16x8*)(vgb + kn);
      va1 = *(const u16x8*)(vgb + kn + 32);
    }

    __syncthreads();   // buf[it&1] visible; prior readers done at barrier it-1

    const int k0 = it * 64;
    if (k0 > qw + 31) continue;   // tile entirely above causal diagonal

    // S^T = K · Q^T  (C: row = key-in-tile = quad*4+r, col = q = mrow)
    f32x4 s[2][4];
#pragma unroll
    for (int nt = 0; nt < 4; ++nt) {
      bf16x8 kf0 = *(const bf16x8*)(buf + 0 * 2048 + (nt * 16 + mrow) * 32 + quad * 8);
      bf16x8 kf1 = *(const bf16x8*)(buf + 1 * 2048 + (nt * 16 + mrow) * 32 + quad * 8);
      f32x4 z0 = (f32x4){0.f, 0.f, 0.f, 0.f};
      z0 = mfma_bf(kf0, qf00, z0);
      s[0][nt] = mfma_bf(kf1, qf01, z0);
      f32x4 z1 = (f32x4){0.f, 0.f, 0.f, 0.f};
      z1 = mfma_bf(kf0, qf10, z1);
      s[1][nt] = mfma_bf(kf1, qf11, z1);
    }

    if (k0 + 63 > qw) {   // diagonal tile for this wave: causal mask
#pragma unroll
      for (int g = 0; g < 2; ++g)
#pragma unroll
        for (int nt = 0; nt < 4; ++nt)
#pragma unroll
          for (int r = 0; r < 4; ++r)
            if (k0 + nt * 16 + quad * 4 + r > qw + g * 16 + mrow)
              s[g][nt][r] = -1e30f;
    }
    // p = exp2(s), no max subtraction (|s| bounded << 127)
#pragma unroll
    for (int g = 0; g < 2; ++g)
#pragma unroll
      for (int nt = 0; nt < 4; ++nt)
#pragma unroll
        for (int r = 0; r < 4; ++r)
          s[g][nt][r] = __builtin_amdgcn_exp2f(s[g][nt][r]);

    // P^T B-frags: compiler pairs casts into v_cvt_pk_bf16_f32 (RNE)
    bf16x8 pf[2][2];
#pragma unroll
    for (int g = 0; g < 2; ++g) {
      pf[g][0] = (bf16x8){(bf16)s[g][0][0], (bf16)s[g][0][1],
                          (bf16)s[g][0][2], (bf16)s[g][0][3],
                          (bf16)s[g][1][0], (bf16)s[g][1][1],
                          (bf16)s[g][1][2], (bf16)s[g][1][3]};
      pf[g][1] = (bf16x8){(bf16)s[g][2][0], (bf16)s[g][2][1],
                          (bf16)s[g][2][2], (bf16)s[g][2][3],
                          (bf16)s[g][3][0], (bf16)s[g][3][1],
                          (bf16)s[g][3][2], (bf16)s[g][3][3]};
      // l row-sum via ones A-frag
      ol[g] = mfma_bf(ones, pf[g][0], ol[g]);
      ol[g] = mfma_bf(ones, pf[g][1], ol[g]);
    }

    // O^T += V^T · P^T  (each vf read feeds both q-groups)
#pragma unroll
    for (int dt = 0; dt < 4; ++dt) {
      bf16x8 vf0 = *(const bf16x8*)(buf + 2 * 2048 + (dt * 16 + mrow) * 32 + quad * 8);
      bf16x8 vf1 = *(const bf16x8*)(buf + 3 * 2048 + (dt * 16 + mrow) * 32 + quad * 8);
      o[0][dt] = mfma_bf(vf0, pf[0][0], o[0][dt]);
      o[0][dt] = mfma_bf(vf1, pf[0][1], o[0][dt]);
      o[1][dt] = mfma_bf(vf0, pf[1][0], o[1][dt]);
      o[1][dt] = mfma_bf(vf1, pf[1][1], o[1][dt]);
    }
  }

  __syncthreads();   // all K/V readers done; reuse smem as Osh[4][32][72]
  u16* Osh = &smem[0][0][0];

  // epilogue: normalize, transpose O^T -> O through per-wave LDS, store
#pragma unroll
  for (int g = 0; g < 2; ++g) {
    const float inv = 1.f / ol[g][0];
#pragma unroll
    for (int dt = 0; dt < 4; ++dt)
#pragma unroll
      for (int r = 0; r < 4; ++r)
        Osh[(w * 32 + g * 16 + mrow) * 72 + dt * 16 + quad * 4 + r] =
            cvt_bf16(o[g][dt][r] * inv);
  }
#pragma unroll
  for (int p = 0; p < 4; ++p) {
    int ql = (lane >> 3) + 8 * p;
    int ch = lane & 7;
    u16x8 v = *(const u16x8*)&Osh[(w * 32 + ql) * 72 + ch * 8];
    int t = q0 + w * 32 + ql;
    *(u16x8*)(aout + ((size_t)(bb * 2048 + t)) * 1024 + h * 64 + ch * 8) = v;
  }
}

extern "C" void kernel_launch(void* const* d_in, const int* in_sizes, int n_in,
                              void* d_out, int out_size, void* d_ws, size_t ws_size,
                              hipStream_t stream) {
  const float* x  = (const float*)d_in[0];
  const float* Wq = (const float*)d_in[1];
  const float* Wk = (const float*)d_in[2];
  const float* Wv = (const float*)d_in[3];
  const float* Wo = (const float*)d_in[4];

  u16* qkv   = (u16*)d_ws;
  u16* vperm = qkv + (size_t)3 * 64 * 2048 * 64;
  u16* aout  = vperm + (size_t)64 * 64 * 2048;
  u16* xtok  = aout + (size_t)8192 * 1024;
  u16* xpos  = xtok + (size_t)8192 * 512;
  u16* Wt    = xpos + (size_t)8192 * 512;
  u16* WoT   = Wt + (size_t)3 * 1024 * 512;
  float* out = (float*)d_out;

  prep<<<dim3(1024 + 8192), dim3(256), 0, stream>>>(x, Wq, Wk, Wv, Wo, xtok,
                                                    xpos, Wt, WoT);
  gemm_qkv128<<<dim3(4, 64, 3), dim3(512), 0, stream>>>(xtok, xpos, Wt, qkv, vperm);
  attn<<<dim3(64, 16), dim3(256), 0, stream>>>(qkv, vperm, aout);
  gemm_out128<<<dim3(4, 64), dim3(512), 0, stream>>>(aout, WoT, out);
}